// Round 4
// baseline (677.292 us; speedup 1.0000x reference)
//
#include <hip/hip_runtime.h>

typedef unsigned short u16;
typedef __bf16 bfv8 __attribute__((ext_vector_type(8)));
typedef float f32x4 __attribute__((ext_vector_type(4)));
typedef u16 u16x8 __attribute__((ext_vector_type(8)));

#define B_      2
#define T_      2048
#define C_      2048
#define H_      16
#define HD_     128
#define NT_     (B_ * T_)
#define DOWN_N  1088
#define DCAT    1168   // 1088 (down) + 80 (gate logits)
#define DCATP   1280   // DCAT padded to 128 multiple (zero rows) for gload_lds GEMM
#define KV_N    3072
#define Q_N     2048
#define EPS_    1.1920929e-07f
// softmax scale (1/sqrt(128)) * log2(e), for exp2-domain online softmax
#define CEXP    0.12751879524580262f

__device__ __forceinline__ float b2f(u16 u) {
    union { unsigned u; float f; } c; c.u = ((unsigned)u) << 16; return c.f;
}
__device__ __forceinline__ u16 f2b(float f) {
    union { float f; unsigned u; } c; c.f = f;
    return (u16)((c.u + 0x7FFFu + ((c.u >> 16) & 1u)) >> 16);
}
__device__ __forceinline__ float dynload(const void* p, size_t i, int bf) {
    if (bf) return b2f(((const u16*)p)[i]);
    return ((const float*)p)[i];
}

// async global->LDS, 16B per lane (wave-uniform LDS base + lane*16)
__device__ __forceinline__ void gload16(const u16* g, u16* l) {
    __builtin_amdgcn_global_load_lds(
        (const __attribute__((address_space(1))) void*)g,
        (__attribute__((address_space(3))) void*)l,
        16, 0, 0);
}

// ---------------------------------------------------------------------------
// Input dtype detector (writes flag[0] = 1 if bf16).
// ---------------------------------------------------------------------------
__global__ void detect_kernel(const unsigned* __restrict__ x, int* __restrict__ flag) {
    __shared__ int cnt;
    if (threadIdx.x == 0) cnt = 0;
    __syncthreads();
    int c = 0;
    for (int i = threadIdx.x; i < 4096; i += 256) {
        const unsigned w = x[i];
        const unsigned e = (w >> 7) & 0xFF;
        if (e >= 105 && e <= 140) ++c;
    }
    atomicAdd(&cnt, c);
    __syncthreads();
    if (threadIdx.x == 0) flag[0] = (cnt > 2300) ? 1 : 0;
}

// ---------------------------------------------------------------------------
// Elementwise cast (dyn f32/bf16 -> bf16), 8 elems/thread.
// ---------------------------------------------------------------------------
__global__ __launch_bounds__(256) void cast_kernel(
    const void* __restrict__ in, u16* __restrict__ out, int n, const int* __restrict__ flagp)
{
    const int fl = flagp[0];
    const int i0 = (blockIdx.x * 256 + threadIdx.x) * 8;
    if (i0 + 8 > n) return;
    u16x8 o;
    #pragma unroll
    for (int i = 0; i < 8; ++i) o[i] = f2b(dynload(in, (size_t)i0 + i, fl));
    *(u16x8*)(out + i0) = o;
}

// ---------------------------------------------------------------------------
// Transpose + cast: W[K][N] (dyn) -> W_T[N][K] (bf16). 32x32 LDS tiles.
// Rows [N, Ntot) are written as zeros (pad for gload_lds GEMM B-tiles).
// ---------------------------------------------------------------------------
__global__ __launch_bounds__(256) void tcast_kernel(
    const void* __restrict__ in, u16* __restrict__ out, int K, int N, int Ntot,
    const int* __restrict__ flagp)
{
    const int fl = flagp[0];
    __shared__ float sf[32][33];
    const int n0 = blockIdx.x * 32, k0 = blockIdx.y * 32;
    const int tx = threadIdx.x & 31, ty = threadIdx.x >> 5;
    const int cr = (n0 + tx < N) ? (n0 + tx) : (N - 1);   // clamped read col
    #pragma unroll
    for (int i = 0; i < 4; ++i)
        sf[ty + 8 * i][tx] = dynload(in, (size_t)(k0 + ty + 8 * i) * N + cr, fl);
    __syncthreads();
    #pragma unroll
    for (int i = 0; i < 4; ++i) {
        const int n = n0 + ty + 8 * i;
        if (n < Ntot) out[(size_t)n * K + k0 + tx] = (n < N) ? f2b(sf[tx][ty + 8 * i]) : (u16)0;
    }
}

// ---------------------------------------------------------------------------
// MFMA GEMM (m97 structure): C[M,N] = A[M,K] @ B[K,N], A row-major bf16,
// BT = B^T row-major bf16 [N][K] (rows padded so n-tiles are full 128).
// 128x128 tile, BK=32, 4 waves each 64x64 (4x4 of 16x16x32).
// Staging via global_load_lds width=16 into LINEAR (unpadded) LDS.
// ---------------------------------------------------------------------------
__device__ __forceinline__ void stc(u16* p, float v)  { *p = f2b(v); }
__device__ __forceinline__ void stc(float* p, float v){ *p = v; }

template <typename TC>
__global__ __launch_bounds__(256) void mfma_gemm(
    const u16* __restrict__ A, int lda,
    const u16* __restrict__ BT, int ldb,
    TC* __restrict__ Cm, int ldc,
    int M, int N, int K)
{
    __shared__ u16 As[128 * 32];   // linear [m][k], row = 64B
    __shared__ u16 Bs[128 * 32];   // linear [n][k]
    const int tid = threadIdx.x;
    const int m0 = blockIdx.y * 128, n0 = blockIdx.x * 128;
    const int w = tid >> 6, l = tid & 63;
    const int wm = (w >> 1) * 64, wn = (w & 1) * 64;
    const int lr = l & 15, lq = l >> 4;

    f32x4 acc[4][4];
    #pragma unroll
    for (int i = 0; i < 4; ++i)
        #pragma unroll
        for (int j = 0; j < 4; ++j) acc[i][j] = (f32x4){0.f, 0.f, 0.f, 0.f};

    // per-lane global source addresses matching the linear LDS order
    const int srow = w * 32 + (l >> 2);
    const int scol = (l & 3) * 8;
    const u16* ag = A  + (size_t)(m0 + srow) * lda + scol;
    const u16* bg = BT + (size_t)(n0 + srow) * ldb + scol;
    u16* as0 = &As[(w * 32) * 32];
    u16* as1 = &As[(w * 32 + 16) * 32];
    u16* bs0 = &Bs[(w * 32) * 32];
    u16* bs1 = &Bs[(w * 32 + 16) * 32];

    for (int k0 = 0; k0 < K; k0 += 32) {
        gload16(ag + k0,            as0);
        gload16(ag + 16 * lda + k0, as1);
        gload16(bg + k0,            bs0);
        gload16(bg + 16 * ldb + k0, bs1);
        __syncthreads();
        bfv8 af[4], bf[4];
        #pragma unroll
        for (int mi = 0; mi < 4; ++mi) af[mi] = *(const bfv8*)&As[(wm + mi * 16 + lr) * 32 + lq * 8];
        #pragma unroll
        for (int ni = 0; ni < 4; ++ni) bf[ni] = *(const bfv8*)&Bs[(wn + ni * 16 + lr) * 32 + lq * 8];
        #pragma unroll
        for (int mi = 0; mi < 4; ++mi)
            #pragma unroll
            for (int ni = 0; ni < 4; ++ni)
                acc[mi][ni] = __builtin_amdgcn_mfma_f32_16x16x32_bf16(af[mi], bf[ni], acc[mi][ni], 0, 0, 0);
        __syncthreads();
    }

    #pragma unroll
    for (int mi = 0; mi < 4; ++mi) {
        #pragma unroll
        for (int ni = 0; ni < 4; ++ni) {
            const int col = n0 + wn + ni * 16 + lr;
            if (col < N) {
                #pragma unroll
                for (int r = 0; r < 4; ++r) {
                    const int row = m0 + wm + mi * 16 + lq * 4 + r;
                    stc(&Cm[(size_t)row * ldc + col], acc[mi][ni][r]);
                }
            }
        }
    }
}

// ---------------------------------------------------------------------------
// Assemble q/k/v per (b,t): rope + rmsnorm for q,k; gated v with ve einsum.
// ---------------------------------------------------------------------------
__global__ __launch_bounds__(256) void assemble_kernel(
    const u16* __restrict__ down,      // [NT,1168] bf16
    const u16* __restrict__ qraw,      // [NT,2048] bf16
    const u16* __restrict__ kv,        // [NT,3072] bf16
    const void* __restrict__ ve,       // [NT,8192] dyn
    const void* __restrict__ cosg,     // [NT,32]   dyn
    const void* __restrict__ sing,     // [NT,32]   dyn
    u16* __restrict__ qo, u16* __restrict__ ko, u16* __restrict__ vo,
    const int* __restrict__ flagp)
{
    const int fl = flagp[0];
    const int bt = blockIdx.x;
    const int tid = threadIdx.x;
    __shared__ float cs[32], sn[32], kr[64];
    if (tid < 32) {
        cs[tid] = dynload(cosg, (size_t)bt * 32 + tid, fl);
        sn[tid] = dynload(sing, (size_t)bt * 32 + tid, fl);
    }
    __syncthreads();
    if (tid < 64) {
        const u16* rp = down + (size_t)bt * DCAT + 1024;
        const int d = tid;
        if (d < 32) kr[d] = b2f(rp[d]) * cs[d] + b2f(rp[d + 32]) * sn[d];
        else { const int r = d - 32; kr[d] = -b2f(rp[d - 32]) * sn[r] + b2f(rp[d]) * cs[r]; }
    }
    __syncthreads();

    const int h = tid >> 4;
    const int lane = tid & 15;
    const int d0 = lane * 8;

    // Q: rope on [64,128), rmsnorm over 128
    const u16* qr = qraw + (size_t)bt * Q_N + h * HD_;
    float vq[8];
    float ss = 0.f;
    #pragma unroll
    for (int i = 0; i < 8; ++i) {
        const int d = d0 + i;
        float xv = b2f(qr[d]);
        if (d >= 64) {
            if (d < 96) { const int r = d - 64; xv = xv * cs[r] + b2f(qr[d + 32]) * sn[r]; }
            else        { const int r = d - 96; xv = -b2f(qr[d - 32]) * sn[r] + xv * cs[r]; }
        }
        vq[i] = xv; ss += xv * xv;
    }
    #pragma unroll
    for (int off = 1; off < 16; off <<= 1) ss += __shfl_xor(ss, off);
    float rms = rsqrtf(ss * (1.f / 128.f) + EPS_);
    u16* qop = qo + (size_t)bt * Q_N + h * HD_ + d0;
    #pragma unroll
    for (int i = 0; i < 8; ++i) qop[i] = f2b(vq[i] * rms);

    // K: [k_nope(64) | roped k_rope(64)], rmsnorm over 128
    const u16* kvp = kv + (size_t)bt * KV_N + h * 192;
    float vk[8];
    ss = 0.f;
    #pragma unroll
    for (int i = 0; i < 8; ++i) {
        const int d = d0 + i;
        const float xv = (d < 64) ? b2f(kvp[d]) : kr[d - 64];
        vk[i] = xv; ss += xv * xv;
    }
    #pragma unroll
    for (int off = 1; off < 16; off <<= 1) ss += __shfl_xor(ss, off);
    rms = rsqrtf(ss * (1.f / 128.f) + EPS_);
    u16* kop = ko + (size_t)bt * Q_N + h * HD_ + d0;
    #pragma unroll
    for (int i = 0; i < 8; ++i) kop[i] = f2b(vk[i] * rms);

    // V: g0 * v + sum_m g[m+1] * ve[m]; gates = 2*sigmoid(down[1088 + h*5 + j])
    float g[5];
    #pragma unroll
    for (int j = 0; j < 5; ++j) {
        const float logit = b2f(down[(size_t)bt * DCAT + 1088 + h * 5 + j]);
        g[j] = 2.f / (1.f + expf(-logit));
    }
    const u16* vp = kvp + 64;
    const size_t vebase = (size_t)bt * 8192 + h * HD_;
    u16* vop = vo + (size_t)bt * Q_N + h * HD_ + d0;
    #pragma unroll
    for (int i = 0; i < 8; ++i) {
        const int d = d0 + i;
        float val = g[0] * b2f(vp[d]);
        #pragma unroll
        for (int m = 0; m < 4; ++m) val += g[1 + m] * dynload(ve, vebase + m * 2048 + d, fl);
        vop[i] = f2b(val);
    }
}

// ---------------------------------------------------------------------------
// V transpose: vn [b][t][h][d] -> vt [(b,h)][d][t]   (bf16, 64x64 tiles)
// ---------------------------------------------------------------------------
__global__ __launch_bounds__(256) void vtrans_kernel(
    const u16* __restrict__ vn, u16* __restrict__ vt)
{
    __shared__ u16 s[64][72];
    const int t0 = blockIdx.x * 64;
    const int d0 = blockIdx.y * 64;
    const int bh = blockIdx.z;
    const int tid = threadIdx.x;
    {
        const int tt = tid >> 2, seg = tid & 3;
        const u16* p = vn + ((size_t)((bh >> 4) * T_) + t0 + tt) * 2048 + (bh & 15) * 128 + d0 + seg * 16;
        u16x8 v0 = *(const u16x8*)(p);
        u16x8 v1 = *(const u16x8*)(p + 8);
        *(u16x8*)&s[tt][seg * 16]     = v0;
        *(u16x8*)&s[tt][seg * 16 + 8] = v1;
    }
    __syncthreads();
    {
        const int dd = tid >> 2, tseg = tid & 3;
        u16* q = vt + ((size_t)(bh * 128) + d0 + dd) * T_ + t0 + tseg * 16;
        #pragma unroll
        for (int g = 0; g < 2; ++g) {
            u16x8 o;
            #pragma unroll
            for (int i = 0; i < 8; ++i) o[i] = s[tseg * 16 + g * 8 + i][dd];
            *(u16x8*)(q + g * 8) = o;
        }
    }
}

// ---------------------------------------------------------------------------
// MFMA flash attention. Block = 512 threads (8 waves), 128 Q rows.
// 64-key tiles; each wave owns 16 Q rows. Online softmax in registers.
//
// Load-balance mapping: work(mb) = 2mb+2 tiles; complement is mb^15.
// Assign from the flat block id so that BOTH plausible co-resident CU
// pairings are complementary:
//   b  = bit0, h = bits{1,2,3,8}, q = bits{4..7},
//   mb = (bit0^bit8) ? q^15 : q.
// flat^1   (stride-1 pairing):   same h/q, parity flips -> mb complements.
// flat^256 (stride-256 pairing): q same,  parity flips -> mb complements.
// Every pair sums to 34 tile-units; XCD (flat%8) sees mb uniform 0..15.
// ---------------------------------------------------------------------------
__global__ __launch_bounds__(512) void attn_mfma(
    const u16* __restrict__ qn, const u16* __restrict__ kn,
    const u16* __restrict__ vt, u16* __restrict__ yb,
    const int* __restrict__ wptr)
{
    __shared__ u16 Ks[64][136];      // K tile row-major [key][d]
    __shared__ u16 VTs[128][72];     // V tile transposed [d][key]
    __shared__ u16 Ps[8][16][72];    // per-wave P round-trip [qrow][key]

    const int flat = (int)(blockIdx.x + (blockIdx.y << 4) + (blockIdx.z << 8));
    const int b  = flat & 1;
    const int h  = ((flat >> 1) & 7) | ((flat >> 5) & 8);   // bit8 -> h bit3
    const int q4 = (flat >> 4) & 15;
    const int mb = ((flat ^ (flat >> 8)) & 1) ? (q4 ^ 15) : q4;
    const int m0 = mb * 128;
    const int W = wptr[0];
    const int tid = threadIdx.x;
    const int w = tid >> 6, l = tid & 63;
    const int lr = l & 15, lq = l >> 4;
    const int qr0 = m0 + w * 16;

    bfv8 qf[4];
    {
        const u16* qp = qn + ((size_t)(b * T_) + qr0 + lr) * 2048 + h * 128 + lq * 8;
        #pragma unroll
        for (int kk = 0; kk < 4; ++kk) qf[kk] = *(const bfv8*)(qp + kk * 32);
    }

    f32x4 oacc[8];
    #pragma unroll
    for (int i = 0; i < 8; ++i) oacc[i] = (f32x4){0.f, 0.f, 0.f, 0.f};
    float m_r[4] = {-1e30f, -1e30f, -1e30f, -1e30f};
    float l_r[4] = {0.f, 0.f, 0.f, 0.f};

    const int kkey = tid >> 3, kseg = tid & 7;   // K staging: 64 keys x 8 segs of 16
    const int vd = tid >> 2, vh = tid & 3;       // V staging: 128 d x 4 segs of 16

    int ns = m0 - W; if (ns < 0) ns = 0; ns &= ~63;
    const int ne = m0 + 64;                      // inclusive last tile start

    const u16* kbase = kn + ((size_t)(b * T_) + kkey) * 2048 + h * 128 + kseg * 16;
    const u16* vbase = vt + ((size_t)(b * H_ + h) * 128 + vd) * T_ + vh * 16;

    // prologue: prefetch first tile into registers
    u16x8 pk0, pk1, pv0, pv1;
    {
        const u16* kp = kbase + (size_t)ns * 2048;
        const u16* vp = vbase + ns;
        pk0 = *(const u16x8*)(kp);
        pk1 = *(const u16x8*)(kp + 8);
        pv0 = *(const u16x8*)(vp);
        pv1 = *(const u16x8*)(vp + 8);
    }

    for (int n0 = ns; n0 <= ne; n0 += 64) {
        // write previously-fetched tile to LDS (prev compute done: trailing barrier)
        *(u16x8*)&Ks[kkey][kseg * 16]     = pk0;
        *(u16x8*)&Ks[kkey][kseg * 16 + 8] = pk1;
        *(u16x8*)&VTs[vd][vh * 16]        = pv0;
        *(u16x8*)&VTs[vd][vh * 16 + 8]    = pv1;
        __syncthreads();

        // issue next tile's loads now; latency hides under compute below
        if (n0 < ne) {
            const u16* kp = kbase + (size_t)(n0 + 64) * 2048;
            const u16* vp = vbase + (n0 + 64);
            pk0 = *(const u16x8*)(kp);
            pk1 = *(const u16x8*)(kp + 8);
            pv0 = *(const u16x8*)(vp);
            pv1 = *(const u16x8*)(vp + 8);
        }

        // per-wave early-out on fully-masked tiles (barriers stay uniform)
        const bool active = (n0 <= qr0 + 15) && (n0 + 63 >= qr0 - W);
        if (active) {
            // S = Q K^T
            f32x4 s[4];
            #pragma unroll
            for (int f = 0; f < 4; ++f) {
                s[f] = (f32x4){0.f, 0.f, 0.f, 0.f};
                #pragma unroll
                for (int kk = 0; kk < 4; ++kk) {
                    bfv8 kf = *(const bfv8*)&Ks[f * 16 + lr][kk * 32 + lq * 8];
                    s[f] = __builtin_amdgcn_mfma_f32_16x16x32_bf16(qf[kk], kf, s[f], 0, 0, 0);
                }
            }

            if ((n0 + 63 > qr0) || (qr0 + 15 - n0 > W)) {
                #pragma unroll
                for (int f = 0; f < 4; ++f) {
                    const int si = n0 + f * 16 + lr;
                    #pragma unroll
                    for (int r = 0; r < 4; ++r) {
                        const int ti = qr0 + lq * 4 + r;
                        if (si > ti || ti - si > W) s[f][r] = -1e30f;
                    }
                }
            }

            // online softmax (rows in 16-lane groups)
            float al_r[4];
            #pragma unroll
            for (int r = 0; r < 4; ++r) {
                float mx = fmaxf(fmaxf(s[0][r], s[1][r]), fmaxf(s[2][r], s[3][r]));
                mx = fmaxf(mx, __shfl_xor(mx, 1));
                mx = fmaxf(mx, __shfl_xor(mx, 2));
                mx = fmaxf(mx, __shfl_xor(mx, 4));
                mx = fmaxf(mx, __shfl_xor(mx, 8));
                const float mnew = fmaxf(m_r[r], mx);
                al_r[r] = exp2f((m_r[r] - mnew) * CEXP);
                float ps = 0.f;
                #pragma unroll
                for (int f = 0; f < 4; ++f) {
                    const float sv = s[f][r];
                    const float pv = (sv <= -0.9e30f) ? 0.f : exp2f((sv - mnew) * CEXP);
                    s[f][r] = pv; ps += pv;
                }
                ps += __shfl_xor(ps, 1);
                ps += __shfl_xor(ps, 2);
                ps += __shfl_xor(ps, 4);
                ps += __shfl_xor(ps, 8);
                l_r[r] = l_r[r] * al_r[r] + ps;
                m_r[r] = mnew;
            }
            #pragma unroll
            for (int od = 0; od < 8; ++od)
                #pragma unroll
                for (int r = 0; r < 4; ++r) oacc[od][r] *= al_r[r];

            // P -> LDS (C-layout scatter); Ps[w] is wave-private, no barrier
            #pragma unroll
            for (int f = 0; f < 4; ++f)
                #pragma unroll
                for (int r = 0; r < 4; ++r)
                    Ps[w][lq * 4 + r][f * 16 + lr] = f2b(s[f][r]);

            // O += P V
            #pragma unroll
            for (int kk2 = 0; kk2 < 2; ++kk2) {
                bfv8 pf = *(const bfv8*)&Ps[w][lr][kk2 * 32 + lq * 8];
                #pragma unroll
                for (int od = 0; od < 8; ++od) {
                    bfv8 vf = *(const bfv8*)&VTs[od * 16 + lr][kk2 * 32 + lq * 8];
                    oacc[od] = __builtin_amdgcn_mfma_f32_16x16x32_bf16(pf, vf, oacc[od], 0, 0, 0);
                }
            }
        }
        __syncthreads();
    }

    float inv[4];
    #pragma unroll
    for (int r = 0; r < 4; ++r) inv[r] = 1.f / l_r[r];
    #pragma unroll
    for (int od = 0; od < 8; ++od)
        #pragma unroll
        for (int r = 0; r < 4; ++r) {
            const size_t idx = ((size_t)(b * T_) + qr0 + lq * 4 + r) * 2048 + h * 128 + od * 16 + lr;
            yb[idx] = f2b(oacc[od][r] * inv[r]);
        }
}

// ---------------------------------------------------------------------------
extern "C" void kernel_launch(void* const* d_in, const int* in_sizes, int n_in,
                              void* d_out, int out_size, void* d_ws, size_t ws_size,
                              hipStream_t stream)
{
    const void* x      = d_in[0];
    const void* ve     = d_in[1];
    const void* cosg   = d_in[2];
    const void* sing   = d_in[3];
    const void* w_down = d_in[4];
    const void* w_ukv  = d_in[5];
    const void* w_uq   = d_in[6];
    const void* w_gate = d_in[7];
    const void* w_proj = d_in[8];
    const int*  wsz    = (const int*)d_in[9];
    float* out = (float*)d_out;

    // workspace (~121 MB with aliasing)
    char* p = (char*)d_ws;
    u16* xbf    = (u16*)p; p += (size_t)NT_ * C_ * 2;          // reused as qn
    u16* wcatT  = (u16*)p; p += (size_t)DCATP * C_ * 2;        // [w_down|w_gate|0pad]^T
    u16* wukvT  = (u16*)p; p += (size_t)KV_N * 512 * 2;
    u16* wuqT   = (u16*)p; p += (size_t)Q_N * 512 * 2;
    u16* wpT    = (u16*)p; p += (size_t)C_ * C_ * 2;
    u16* downb  = (u16*)p; p += (size_t)NT_ * DCAT * 2;
    u16* kvb    = (u16*)p; p += (size_t)NT_ * KV_N * 2;
    u16* qraw   = (u16*)p; p += (size_t)NT_ * Q_N * 2;         // reused as vtb
    u16* kn     = (u16*)p; p += (size_t)NT_ * Q_N * 2;
    u16* vn     = (u16*)p; p += (size_t)NT_ * Q_N * 2;         // reused as ybf
    int* flag   = (int*)p; p += 256;
    u16* qn  = xbf;    // x_bf dead after down GEMM
    u16* vtb = qraw;   // qraw dead after assemble
    u16* ybf = vn;     // vn dead after vtrans (attn reads vtb)

    dim3 blk(256);
    detect_kernel<<<1, blk, 0, stream>>>((const unsigned*)x, flag);
    cast_kernel<<<dim3(NT_ * C_ / (256 * 8)), blk, 0, stream>>>(x, xbf, NT_ * C_, flag);
    tcast_kernel<<<dim3(DOWN_N / 32, C_ / 32), blk, 0, stream>>>(w_down, wcatT, C_, DOWN_N, DOWN_N, flag);
    // gate cols + zero-pad rows up to DCATP (192 rows total from offset 1088)
    tcast_kernel<<<dim3((DCATP - DOWN_N) / 32, C_ / 32), blk, 0, stream>>>(
        w_gate, wcatT + (size_t)DOWN_N * C_, C_, 80, DCATP - DOWN_N, flag);
    tcast_kernel<<<dim3(KV_N / 32, 512 / 32), blk, 0, stream>>>(w_ukv, wukvT, 512, KV_N, KV_N, flag);
    tcast_kernel<<<dim3(Q_N / 32, 512 / 32), blk, 0, stream>>>(w_uq, wuqT, 512, Q_N, Q_N, flag);
    tcast_kernel<<<dim3(C_ / 32, C_ / 32), blk, 0, stream>>>(w_proj, wpT, C_, C_, C_, flag);

    // down+gates = x @ [w_down|w_gate] -> bf16 [4096,1168] (B padded to 1280 rows)
    mfma_gemm<u16><<<dim3(DCATP / 128, NT_ / 128), blk, 0, stream>>>(
        xbf, C_, wcatT, C_, downb, DCAT, NT_, DCAT, C_);
    // kv = c_kv @ w_ukv -> bf16 [4096,3072]
    mfma_gemm<u16><<<dim3(KV_N / 128, NT_ / 128), blk, 0, stream>>>(
        downb, DCAT, wukvT, 512, kvb, KV_N, NT_, KV_N, 512);
    // q_raw = c_q @ w_uq -> bf16 [4096,2048]
    mfma_gemm<u16><<<dim3(Q_N / 128, NT_ / 128), blk, 0, stream>>>(
        downb + 512, DCAT, wuqT, 512, qraw, Q_N, NT_, Q_N, 512);
    // assemble q/k/v (incl. gate sigmoid from down logits)
    assemble_kernel<<<dim3(NT_), blk, 0, stream>>>(
        downb, qraw, kvb, ve, cosg, sing, qn, kn, vn, flag);
    // v transpose to [(b,h)][d][t]
    vtrans_kernel<<<dim3(T_ / 64, 2, B_ * H_), blk, 0, stream>>>(vn, vtb);
    // flash attention -> y bf16
    attn_mfma<<<dim3(T_ / 128, H_, B_), dim3(512), 0, stream>>>(qn, kn, vtb, ybf, wsz);
    // out = y @ w_proj -> f32
    mfma_gemm<float><<<dim3(Q_N / 128, NT_ / 128), blk, 0, stream>>>(
        ybf, Q_N, wpT, C_, out, C_, NT_, C_, Q_N);
}

// Round 5
// 659.638 us; speedup vs baseline: 1.0268x; 1.0268x over previous
//
#include <hip/hip_runtime.h>

typedef unsigned short u16;
typedef __bf16 bfv8 __attribute__((ext_vector_type(8)));
typedef float f32x4 __attribute__((ext_vector_type(4)));
typedef u16 u16x8 __attribute__((ext_vector_type(8)));

#define B_      2
#define T_      2048
#define C_      2048
#define H_      16
#define HD_     128
#define NT_     (B_ * T_)
#define DOWN_N  1088
#define DCAT    1168   // 1088 (down) + 80 (gate logits)
#define DCATP   1280   // DCAT padded to 128 multiple (zero rows) for gload_lds GEMM
#define KV_N    3072
#define Q_N     2048
#define EPS_    1.1920929e-07f
// softmax scale (1/sqrt(128)) * log2(e), for exp2-domain online softmax
#define CEXP    0.12751879524580262f
// fixed softmax "max": q,k rmsnormed -> |s|*CEXP <= 128*CEXP = 16.33 (+bf16 slop)
#define SMAXS   16.6f

__device__ __forceinline__ float b2f(u16 u) {
    union { unsigned u; float f; } c; c.u = ((unsigned)u) << 16; return c.f;
}
__device__ __forceinline__ u16 f2b(float f) {
    union { float f; unsigned u; } c; c.f = f;
    return (u16)((c.u + 0x7FFFu + ((c.u >> 16) & 1u)) >> 16);
}
__device__ __forceinline__ float dynload(const void* p, size_t i, int bf) {
    if (bf) return b2f(((const u16*)p)[i]);
    return ((const float*)p)[i];
}

// async global->LDS, 16B per lane (wave-uniform LDS base + lane*16)
__device__ __forceinline__ void gload16(const u16* g, u16* l) {
    __builtin_amdgcn_global_load_lds(
        (const __attribute__((address_space(1))) void*)g,
        (__attribute__((address_space(3))) void*)l,
        16, 0, 0);
}

// ---------------------------------------------------------------------------
// Input dtype detector (writes flag[0] = 1 if bf16).
// ---------------------------------------------------------------------------
__global__ void detect_kernel(const unsigned* __restrict__ x, int* __restrict__ flag) {
    __shared__ int cnt;
    if (threadIdx.x == 0) cnt = 0;
    __syncthreads();
    int c = 0;
    for (int i = threadIdx.x; i < 4096; i += 256) {
        const unsigned w = x[i];
        const unsigned e = (w >> 7) & 0xFF;
        if (e >= 105 && e <= 140) ++c;
    }
    atomicAdd(&cnt, c);
    __syncthreads();
    if (threadIdx.x == 0) flag[0] = (cnt > 2300) ? 1 : 0;
}

// ---------------------------------------------------------------------------
// Elementwise cast (dyn f32/bf16 -> bf16), 8 elems/thread.
// ---------------------------------------------------------------------------
__global__ __launch_bounds__(256) void cast_kernel(
    const void* __restrict__ in, u16* __restrict__ out, int n, const int* __restrict__ flagp)
{
    const int fl = flagp[0];
    const int i0 = (blockIdx.x * 256 + threadIdx.x) * 8;
    if (i0 + 8 > n) return;
    u16x8 o;
    #pragma unroll
    for (int i = 0; i < 8; ++i) o[i] = f2b(dynload(in, (size_t)i0 + i, fl));
    *(u16x8*)(out + i0) = o;
}

// ---------------------------------------------------------------------------
// Transpose + cast: W[K][N] (dyn) -> W_T[N][K] (bf16). 32x32 LDS tiles.
// Rows [N, Ntot) are written as zeros (pad for gload_lds GEMM B-tiles).
// ---------------------------------------------------------------------------
__global__ __launch_bounds__(256) void tcast_kernel(
    const void* __restrict__ in, u16* __restrict__ out, int K, int N, int Ntot,
    const int* __restrict__ flagp)
{
    const int fl = flagp[0];
    __shared__ float sf[32][33];
    const int n0 = blockIdx.x * 32, k0 = blockIdx.y * 32;
    const int tx = threadIdx.x & 31, ty = threadIdx.x >> 5;
    const int cr = (n0 + tx < N) ? (n0 + tx) : (N - 1);   // clamped read col
    #pragma unroll
    for (int i = 0; i < 4; ++i)
        sf[ty + 8 * i][tx] = dynload(in, (size_t)(k0 + ty + 8 * i) * N + cr, fl);
    __syncthreads();
    #pragma unroll
    for (int i = 0; i < 4; ++i) {
        const int n = n0 + ty + 8 * i;
        if (n < Ntot) out[(size_t)n * K + k0 + tx] = (n < N) ? f2b(sf[tx][ty + 8 * i]) : (u16)0;
    }
}

// ---------------------------------------------------------------------------
// MFMA GEMM (m97 structure): C[M,N] = A[M,K] @ B[K,N], A row-major bf16,
// BT = B^T row-major bf16 [N][K] (rows padded so n-tiles are full 128).
// 128x128 tile, BK=32, 4 waves each 64x64 (4x4 of 16x16x32).
// Staging via global_load_lds width=16 into LINEAR (unpadded) LDS.
// ---------------------------------------------------------------------------
__device__ __forceinline__ void stc(u16* p, float v)  { *p = f2b(v); }
__device__ __forceinline__ void stc(float* p, float v){ *p = v; }

template <typename TC>
__global__ __launch_bounds__(256) void mfma_gemm(
    const u16* __restrict__ A, int lda,
    const u16* __restrict__ BT, int ldb,
    TC* __restrict__ Cm, int ldc,
    int M, int N, int K)
{
    __shared__ u16 As[128 * 32];   // linear [m][k], row = 64B
    __shared__ u16 Bs[128 * 32];   // linear [n][k]
    const int tid = threadIdx.x;
    const int m0 = blockIdx.y * 128, n0 = blockIdx.x * 128;
    const int w = tid >> 6, l = tid & 63;
    const int wm = (w >> 1) * 64, wn = (w & 1) * 64;
    const int lr = l & 15, lq = l >> 4;

    f32x4 acc[4][4];
    #pragma unroll
    for (int i = 0; i < 4; ++i)
        #pragma unroll
        for (int j = 0; j < 4; ++j) acc[i][j] = (f32x4){0.f, 0.f, 0.f, 0.f};

    // per-lane global source addresses matching the linear LDS order
    const int srow = w * 32 + (l >> 2);
    const int scol = (l & 3) * 8;
    const u16* ag = A  + (size_t)(m0 + srow) * lda + scol;
    const u16* bg = BT + (size_t)(n0 + srow) * ldb + scol;
    u16* as0 = &As[(w * 32) * 32];
    u16* as1 = &As[(w * 32 + 16) * 32];
    u16* bs0 = &Bs[(w * 32) * 32];
    u16* bs1 = &Bs[(w * 32 + 16) * 32];

    for (int k0 = 0; k0 < K; k0 += 32) {
        gload16(ag + k0,            as0);
        gload16(ag + 16 * lda + k0, as1);
        gload16(bg + k0,            bs0);
        gload16(bg + 16 * ldb + k0, bs1);
        __syncthreads();
        bfv8 af[4], bf[4];
        #pragma unroll
        for (int mi = 0; mi < 4; ++mi) af[mi] = *(const bfv8*)&As[(wm + mi * 16 + lr) * 32 + lq * 8];
        #pragma unroll
        for (int ni = 0; ni < 4; ++ni) bf[ni] = *(const bfv8*)&Bs[(wn + ni * 16 + lr) * 32 + lq * 8];
        #pragma unroll
        for (int mi = 0; mi < 4; ++mi)
            #pragma unroll
            for (int ni = 0; ni < 4; ++ni)
                acc[mi][ni] = __builtin_amdgcn_mfma_f32_16x16x32_bf16(af[mi], bf[ni], acc[mi][ni], 0, 0, 0);
        __syncthreads();
    }

    #pragma unroll
    for (int mi = 0; mi < 4; ++mi) {
        #pragma unroll
        for (int ni = 0; ni < 4; ++ni) {
            const int col = n0 + wn + ni * 16 + lr;
            if (col < N) {
                #pragma unroll
                for (int r = 0; r < 4; ++r) {
                    const int row = m0 + wm + mi * 16 + lq * 4 + r;
                    stc(&Cm[(size_t)row * ldc + col], acc[mi][ni][r]);
                }
            }
        }
    }
}

// ---------------------------------------------------------------------------
// Assemble q/k/v per (b,t): rope + rmsnorm for q,k; gated v with ve einsum.
// ---------------------------------------------------------------------------
__global__ __launch_bounds__(256) void assemble_kernel(
    const u16* __restrict__ down,      // [NT,1168] bf16
    const u16* __restrict__ qraw,      // [NT,2048] bf16
    const u16* __restrict__ kv,        // [NT,3072] bf16
    const void* __restrict__ ve,       // [NT,8192] dyn
    const void* __restrict__ cosg,     // [NT,32]   dyn
    const void* __restrict__ sing,     // [NT,32]   dyn
    u16* __restrict__ qo, u16* __restrict__ ko, u16* __restrict__ vo,
    const int* __restrict__ flagp)
{
    const int fl = flagp[0];
    const int bt = blockIdx.x;
    const int tid = threadIdx.x;
    __shared__ float cs[32], sn[32], kr[64];
    if (tid < 32) {
        cs[tid] = dynload(cosg, (size_t)bt * 32 + tid, fl);
        sn[tid] = dynload(sing, (size_t)bt * 32 + tid, fl);
    }
    __syncthreads();
    if (tid < 64) {
        const u16* rp = down + (size_t)bt * DCAT + 1024;
        const int d = tid;
        if (d < 32) kr[d] = b2f(rp[d]) * cs[d] + b2f(rp[d + 32]) * sn[d];
        else { const int r = d - 32; kr[d] = -b2f(rp[d - 32]) * sn[r] + b2f(rp[d]) * cs[r]; }
    }
    __syncthreads();

    const int h = tid >> 4;
    const int lane = tid & 15;
    const int d0 = lane * 8;

    // Q: rope on [64,128), rmsnorm over 128
    const u16* qr = qraw + (size_t)bt * Q_N + h * HD_;
    float vq[8];
    float ss = 0.f;
    #pragma unroll
    for (int i = 0; i < 8; ++i) {
        const int d = d0 + i;
        float xv = b2f(qr[d]);
        if (d >= 64) {
            if (d < 96) { const int r = d - 64; xv = xv * cs[r] + b2f(qr[d + 32]) * sn[r]; }
            else        { const int r = d - 96; xv = -b2f(qr[d - 32]) * sn[r] + xv * cs[r]; }
        }
        vq[i] = xv; ss += xv * xv;
    }
    #pragma unroll
    for (int off = 1; off < 16; off <<= 1) ss += __shfl_xor(ss, off);
    float rms = rsqrtf(ss * (1.f / 128.f) + EPS_);
    u16* qop = qo + (size_t)bt * Q_N + h * HD_ + d0;
    #pragma unroll
    for (int i = 0; i < 8; ++i) qop[i] = f2b(vq[i] * rms);

    // K: [k_nope(64) | roped k_rope(64)], rmsnorm over 128
    const u16* kvp = kv + (size_t)bt * KV_N + h * 192;
    float vk[8];
    ss = 0.f;
    #pragma unroll
    for (int i = 0; i < 8; ++i) {
        const int d = d0 + i;
        const float xv = (d < 64) ? b2f(kvp[d]) : kr[d - 64];
        vk[i] = xv; ss += xv * xv;
    }
    #pragma unroll
    for (int off = 1; off < 16; off <<= 1) ss += __shfl_xor(ss, off);
    rms = rsqrtf(ss * (1.f / 128.f) + EPS_);
    u16* kop = ko + (size_t)bt * Q_N + h * HD_ + d0;
    #pragma unroll
    for (int i = 0; i < 8; ++i) kop[i] = f2b(vk[i] * rms);

    // V: g0 * v + sum_m g[m+1] * ve[m]; gates = 2*sigmoid(down[1088 + h*5 + j])
    float g[5];
    #pragma unroll
    for (int j = 0; j < 5; ++j) {
        const float logit = b2f(down[(size_t)bt * DCAT + 1088 + h * 5 + j]);
        g[j] = 2.f / (1.f + expf(-logit));
    }
    const u16* vp = kvp + 64;
    const size_t vebase = (size_t)bt * 8192 + h * HD_;
    u16* vop = vo + (size_t)bt * Q_N + h * HD_ + d0;
    #pragma unroll
    for (int i = 0; i < 8; ++i) {
        const int d = d0 + i;
        float val = g[0] * b2f(vp[d]);
        #pragma unroll
        for (int m = 0; m < 4; ++m) val += g[1 + m] * dynload(ve, vebase + m * 2048 + d, fl);
        vop[i] = f2b(val);
    }
}

// ---------------------------------------------------------------------------
// V transpose: vn [b][t][h][d] -> vt [(b,h)][d][t]   (bf16, 64x64 tiles)
// ---------------------------------------------------------------------------
__global__ __launch_bounds__(256) void vtrans_kernel(
    const u16* __restrict__ vn, u16* __restrict__ vt)
{
    __shared__ u16 s[64][72];
    const int t0 = blockIdx.x * 64;
    const int d0 = blockIdx.y * 64;
    const int bh = blockIdx.z;
    const int tid = threadIdx.x;
    {
        const int tt = tid >> 2, seg = tid & 3;
        const u16* p = vn + ((size_t)((bh >> 4) * T_) + t0 + tt) * 2048 + (bh & 15) * 128 + d0 + seg * 16;
        u16x8 v0 = *(const u16x8*)(p);
        u16x8 v1 = *(const u16x8*)(p + 8);
        *(u16x8*)&s[tt][seg * 16]     = v0;
        *(u16x8*)&s[tt][seg * 16 + 8] = v1;
    }
    __syncthreads();
    {
        const int dd = tid >> 2, tseg = tid & 3;
        u16* q = vt + ((size_t)(bh * 128) + d0 + dd) * T_ + t0 + tseg * 16;
        #pragma unroll
        for (int g = 0; g < 2; ++g) {
            u16x8 o;
            #pragma unroll
            for (int i = 0; i < 8; ++i) o[i] = s[tseg * 16 + g * 8 + i][dd];
            *(u16x8*)(q + g * 8) = o;
        }
    }
}

// ---------------------------------------------------------------------------
// MFMA flash attention v2. Block = 256 threads (4 waves), 128 Q rows;
// each wave owns 32 Q rows (2 row-tiles of 16). 64-key tiles.
//
// FIXED-MAX softmax: q,k are rmsnormed so |q.k|*scale*log2e <= 16.33.
// P = exp2(s*CEXP - SMAXS) needs no running max / rescale / reduce shfls;
// the final 1/l divide cancels the constant. Row sums l accumulate via an
// extra ones-column MFMA (VTs rows 128..143: row 128 = 1.0, rest 0).
//
// This cuts LDS-pipe work/block-tile ~2.5x vs v1 (the measured bottleneck:
// MfmaUtil 8.7 / VALU 27 / HBM 3% but ~85us of LDS-pipe occupancy).
// ---------------------------------------------------------------------------
__global__ __launch_bounds__(256) void attn_mfma(
    const u16* __restrict__ qn, const u16* __restrict__ kn,
    const u16* __restrict__ vt, u16* __restrict__ yb,
    const int* __restrict__ wptr)
{
    __shared__ u16 Ks[64][136];      // K tile row-major [key][d]
    __shared__ u16 VTs[144][72];     // V^T tile [d][key]; rows 128..143 = ones-block
    __shared__ u16 Ps[4][32][72];    // per-wave P round-trip [qrow][key]

    const int flat = (int)(blockIdx.x + (blockIdx.y << 4) + (blockIdx.z << 8));
    const int b  = flat & 1;
    const int h  = ((flat >> 1) & 7) | ((flat >> 5) & 8);   // bit8 -> h bit3
    const int q4 = (flat >> 4) & 15;
    const int mb = ((flat ^ (flat >> 8)) & 1) ? (q4 ^ 15) : q4;
    const int m0 = mb * 128;
    const int W = wptr[0];
    const int tid = threadIdx.x;
    const int w = tid >> 6, l = tid & 63;
    const int lr = l & 15, lq = l >> 4;
    const int qr0 = m0 + w * 32;

    // Q fragments: 2 row-tiles x 4 k-slices
    bfv8 qf[2][4];
    #pragma unroll
    for (int mi = 0; mi < 2; ++mi) {
        const u16* qp = qn + ((size_t)(b * T_) + qr0 + mi * 16 + lr) * 2048 + h * 128 + lq * 8;
        #pragma unroll
        for (int kk = 0; kk < 4; ++kk) qf[mi][kk] = *(const bfv8*)(qp + kk * 32);
    }

    f32x4 oacc[2][8];
    f32x4 lacc[2];
    #pragma unroll
    for (int mi = 0; mi < 2; ++mi) {
        lacc[mi] = (f32x4){0.f, 0.f, 0.f, 0.f};
        #pragma unroll
        for (int od = 0; od < 8; ++od) oacc[mi][od] = (f32x4){0.f, 0.f, 0.f, 0.f};
    }

    // static ones-block: VTs row 128 = 1.0, rows 129..143 = 0 (cols 0..63)
    {
        const int rr = 128 + (tid >> 4), cc = (tid & 15) * 4;
        const u16 v = (tid >> 4) == 0 ? (u16)0x3F80 : (u16)0;
        VTs[rr][cc] = v; VTs[rr][cc + 1] = v; VTs[rr][cc + 2] = v; VTs[rr][cc + 3] = v;
    }

    // staging indices (256 threads, 64B contiguous per thread)
    const int kkey = tid >> 2, kq = tid & 3;     // K: 64 rows x 4 segs of 32 u16
    const int vd = tid >> 1, vh2 = tid & 1;      // V: 128 rows x 2 segs of 32 u16

    int ns = m0 - W; if (ns < 0) ns = 0; ns &= ~63;
    const int ne = m0 + 64;                      // inclusive last tile start

    const u16* kbase = kn + ((size_t)(b * T_) + kkey) * 2048 + h * 128 + kq * 32;
    const u16* vbase = vt + ((size_t)(b * H_ + h) * 128 + vd) * T_ + vh2 * 32;

    // prologue: prefetch first tile into registers (T14)
    u16x8 pk[4], pv[4];
    {
        const u16* kp = kbase + (size_t)ns * 2048;
        const u16* vp = vbase + ns;
        #pragma unroll
        for (int s = 0; s < 4; ++s) pk[s] = *(const u16x8*)(kp + s * 8);
        #pragma unroll
        for (int s = 0; s < 4; ++s) pv[s] = *(const u16x8*)(vp + s * 8);
    }

    for (int n0 = ns; n0 <= ne; n0 += 64) {
        {   // write previously-fetched tile to LDS
            u16* kd = &Ks[kkey][kq * 32];
            #pragma unroll
            for (int s = 0; s < 4; ++s) *(u16x8*)(kd + s * 8) = pk[s];
            u16* vdst = &VTs[vd][vh2 * 32];
            #pragma unroll
            for (int s = 0; s < 4; ++s) *(u16x8*)(vdst + s * 8) = pv[s];
        }
        __syncthreads();

        // issue next tile's loads; latency hides under compute below
        if (n0 < ne) {
            const u16* kp = kbase + (size_t)(n0 + 64) * 2048;
            const u16* vp = vbase + (n0 + 64);
            #pragma unroll
            for (int s = 0; s < 4; ++s) pk[s] = *(const u16x8*)(kp + s * 8);
            #pragma unroll
            for (int s = 0; s < 4; ++s) pv[s] = *(const u16x8*)(vp + s * 8);
        }

        // per-wave early-out on fully-masked tiles (barriers stay uniform)
        const bool active = (n0 <= qr0 + 31) && (n0 + 63 >= qr0 - W);
        if (active) {
            // S = Q K^T for both row-tiles (K fragments shared)
            f32x4 s0[4], s1[4];
            #pragma unroll
            for (int f = 0; f < 4; ++f) {
                f32x4 a0 = (f32x4){0.f, 0.f, 0.f, 0.f};
                f32x4 a1 = (f32x4){0.f, 0.f, 0.f, 0.f};
                #pragma unroll
                for (int kk = 0; kk < 4; ++kk) {
                    bfv8 kf = *(const bfv8*)&Ks[f * 16 + lr][kk * 32 + lq * 8];
                    a0 = __builtin_amdgcn_mfma_f32_16x16x32_bf16(qf[0][kk], kf, a0, 0, 0, 0);
                    a1 = __builtin_amdgcn_mfma_f32_16x16x32_bf16(qf[1][kk], kf, a1, 0, 0, 0);
                }
                s0[f] = a0; s1[f] = a1;
            }

            if ((n0 + 63 > qr0) || (qr0 + 31 - n0 > W)) {
                #pragma unroll
                for (int f = 0; f < 4; ++f) {
                    const int si = n0 + f * 16 + lr;
                    #pragma unroll
                    for (int r = 0; r < 4; ++r) {
                        const int t0i = qr0 + lq * 4 + r;
                        const int t1i = t0i + 16;
                        if (si > t0i || t0i - si > W) s0[f][r] = -1e30f;
                        if (si > t1i || t1i - si > W) s1[f][r] = -1e30f;
                    }
                }
            }

            // fixed-max exponent + P -> LDS (Ps[w] wave-private, no barrier)
            #pragma unroll
            for (int f = 0; f < 4; ++f)
                #pragma unroll
                for (int r = 0; r < 4; ++r) {
                    const float p0 = exp2f(s0[f][r] * CEXP - SMAXS);
                    const float p1 = exp2f(s1[f][r] * CEXP - SMAXS);
                    Ps[w][lq * 4 + r][f * 16 + lr]      = f2b(p0);
                    Ps[w][16 + lq * 4 + r][f * 16 + lr] = f2b(p1);
                }

            // O += P V ; l += P 1 (ones-block)
            bfv8 pf0[2], pf1[2];
            #pragma unroll
            for (int kk2 = 0; kk2 < 2; ++kk2) {
                pf0[kk2] = *(const bfv8*)&Ps[w][lr][kk2 * 32 + lq * 8];
                pf1[kk2] = *(const bfv8*)&Ps[w][16 + lr][kk2 * 32 + lq * 8];
            }
            #pragma unroll
            for (int kk2 = 0; kk2 < 2; ++kk2) {
                #pragma unroll
                for (int od = 0; od < 8; ++od) {
                    bfv8 vf = *(const bfv8*)&VTs[od * 16 + lr][kk2 * 32 + lq * 8];
                    oacc[0][od] = __builtin_amdgcn_mfma_f32_16x16x32_bf16(pf0[kk2], vf, oacc[0][od], 0, 0, 0);
                    oacc[1][od] = __builtin_amdgcn_mfma_f32_16x16x32_bf16(pf1[kk2], vf, oacc[1][od], 0, 0, 0);
                }
                bfv8 vf1 = *(const bfv8*)&VTs[128 + lr][kk2 * 32 + lq * 8];
                lacc[0] = __builtin_amdgcn_mfma_f32_16x16x32_bf16(pf0[kk2], vf1, lacc[0], 0, 0, 0);
                lacc[1] = __builtin_amdgcn_mfma_f32_16x16x32_bf16(pf1[kk2], vf1, lacc[1], 0, 0, 0);
            }
        }
        __syncthreads();
    }

    // epilogue: l sits in lanes lr==0 (ones column = d 128); broadcast + divide
    #pragma unroll
    for (int mi = 0; mi < 2; ++mi) {
        float linv[4];
        #pragma unroll
        for (int r = 0; r < 4; ++r) {
            const float lv = __shfl(lacc[mi][r], l & 48);
            linv[r] = 1.f / lv;
        }
        #pragma unroll
        for (int od = 0; od < 8; ++od)
            #pragma unroll
            for (int r = 0; r < 4; ++r) {
                const size_t idx = ((size_t)(b * T_) + qr0 + mi * 16 + lq * 4 + r) * 2048
                                 + h * 128 + od * 16 + lr;
                yb[idx] = f2b(oacc[mi][od][r] * linv[r]);
            }
    }
}

// ---------------------------------------------------------------------------
extern "C" void kernel_launch(void* const* d_in, const int* in_sizes, int n_in,
                              void* d_out, int out_size, void* d_ws, size_t ws_size,
                              hipStream_t stream)
{
    const void* x      = d_in[0];
    const void* ve     = d_in[1];
    const void* cosg   = d_in[2];
    const void* sing   = d_in[3];
    const void* w_down = d_in[4];
    const void* w_ukv  = d_in[5];
    const void* w_uq   = d_in[6];
    const void* w_gate = d_in[7];
    const void* w_proj = d_in[8];
    const int*  wsz    = (const int*)d_in[9];
    float* out = (float*)d_out;

    // workspace (~121 MB with aliasing)
    char* p = (char*)d_ws;
    u16* xbf    = (u16*)p; p += (size_t)NT_ * C_ * 2;          // reused as qn
    u16* wcatT  = (u16*)p; p += (size_t)DCATP * C_ * 2;        // [w_down|w_gate|0pad]^T
    u16* wukvT  = (u16*)p; p += (size_t)KV_N * 512 * 2;
    u16* wuqT   = (u16*)p; p += (size_t)Q_N * 512 * 2;
    u16* wpT    = (u16*)p; p += (size_t)C_ * C_ * 2;
    u16* downb  = (u16*)p; p += (size_t)NT_ * DCAT * 2;
    u16* kvb    = (u16*)p; p += (size_t)NT_ * KV_N * 2;
    u16* qraw   = (u16*)p; p += (size_t)NT_ * Q_N * 2;         // reused as vtb
    u16* kn     = (u16*)p; p += (size_t)NT_ * Q_N * 2;
    u16* vn     = (u16*)p; p += (size_t)NT_ * Q_N * 2;         // reused as ybf
    int* flag   = (int*)p; p += 256;
    u16* qn  = xbf;    // x_bf dead after down GEMM
    u16* vtb = qraw;   // qraw dead after assemble
    u16* ybf = vn;     // vn dead after vtrans (attn reads vtb)

    dim3 blk(256);
    detect_kernel<<<1, blk, 0, stream>>>((const unsigned*)x, flag);
    cast_kernel<<<dim3(NT_ * C_ / (256 * 8)), blk, 0, stream>>>(x, xbf, NT_ * C_, flag);
    tcast_kernel<<<dim3(DOWN_N / 32, C_ / 32), blk, 0, stream>>>(w_down, wcatT, C_, DOWN_N, DOWN_N, flag);
    // gate cols + zero-pad rows up to DCATP (192 rows total from offset 1088)
    tcast_kernel<<<dim3((DCATP - DOWN_N) / 32, C_ / 32), blk, 0, stream>>>(
        w_gate, wcatT + (size_t)DOWN_N * C_, C_, 80, DCATP - DOWN_N, flag);
    tcast_kernel<<<dim3(KV_N / 32, 512 / 32), blk, 0, stream>>>(w_ukv, wukvT, 512, KV_N, KV_N, flag);
    tcast_kernel<<<dim3(Q_N / 32, 512 / 32), blk, 0, stream>>>(w_uq, wuqT, 512, Q_N, Q_N, flag);
    tcast_kernel<<<dim3(C_ / 32, C_ / 32), blk, 0, stream>>>(w_proj, wpT, C_, C_, C_, flag);

    // down+gates = x @ [w_down|w_gate] -> bf16 [4096,1168] (B padded to 1280 rows)
    mfma_gemm<u16><<<dim3(DCATP / 128, NT_ / 128), blk, 0, stream>>>(
        xbf, C_, wcatT, C_, downb, DCAT, NT_, DCAT, C_);
    // kv = c_kv @ w_ukv -> bf16 [4096,3072]
    mfma_gemm<u16><<<dim3(KV_N / 128, NT_ / 128), blk, 0, stream>>>(
        downb, DCAT, wukvT, 512, kvb, KV_N, NT_, KV_N, 512);
    // q_raw = c_q @ w_uq -> bf16 [4096,2048]
    mfma_gemm<u16><<<dim3(Q_N / 128, NT_ / 128), blk, 0, stream>>>(
        downb + 512, DCAT, wuqT, 512, qraw, Q_N, NT_, Q_N, 512);
    // assemble q/k/v (incl. gate sigmoid from down logits)
    assemble_kernel<<<dim3(NT_), blk, 0, stream>>>(
        downb, qraw, kvb, ve, cosg, sing, qn, kn, vn, flag);
    // v transpose to [(b,h)][d][t]
    vtrans_kernel<<<dim3(T_ / 64, 2, B_ * H_), blk, 0, stream>>>(vn, vtb);
    // flash attention -> y bf16
    attn_mfma<<<dim3(T_ / 128, H_, B_), dim3(256), 0, stream>>>(qn, kn, vtb, ybf, wsz);
    // out = y @ w_proj -> f32
    mfma_gemm<float><<<dim3(Q_N / 128, NT_ / 128), blk, 0, stream>>>(
        ybf, Q_N, wpT, C_, out, C_, NT_, C_, Q_N);
}

// Round 6
// 659.171 us; speedup vs baseline: 1.0275x; 1.0007x over previous
//
#include <hip/hip_runtime.h>

typedef unsigned short u16;
typedef __bf16 bfv8 __attribute__((ext_vector_type(8)));
typedef float f32x4 __attribute__((ext_vector_type(4)));
typedef u16 u16x8 __attribute__((ext_vector_type(8)));

#define B_      2
#define T_      2048
#define C_      2048
#define H_      16
#define HD_     128
#define NT_     (B_ * T_)
#define DOWN_N  1088
#define DCAT    1168   // 1088 (down) + 80 (gate logits)
#define DCATP   1280   // DCAT padded to 128 multiple (zero rows) for gload_lds GEMM
#define KV_N    3072
#define Q_N     2048
#define EPS_    1.1920929e-07f
// softmax scale (1/sqrt(128)) * log2(e), for exp2-domain online softmax
#define CEXP    0.12751879524580262f
// fixed softmax "max": q,k rmsnormed -> |s|*CEXP <= 128*CEXP = 16.33 (+bf16 slop)
#define SMAXS   16.6f

__device__ __forceinline__ float b2f(u16 u) {
    union { unsigned u; float f; } c; c.u = ((unsigned)u) << 16; return c.f;
}
__device__ __forceinline__ u16 f2b(float f) {
    union { float f; unsigned u; } c; c.f = f;
    return (u16)((c.u + 0x7FFFu + ((c.u >> 16) & 1u)) >> 16);
}
__device__ __forceinline__ float dynload(const void* p, size_t i, int bf) {
    if (bf) return b2f(((const u16*)p)[i]);
    return ((const float*)p)[i];
}

// async global->LDS, 16B per lane (wave-uniform LDS base + lane*16)
__device__ __forceinline__ void gload16(const u16* g, u16* l) {
    __builtin_amdgcn_global_load_lds(
        (const __attribute__((address_space(1))) void*)g,
        (__attribute__((address_space(3))) void*)l,
        16, 0, 0);
}

// ---------------------------------------------------------------------------
// Input dtype detector (writes flag[0] = 1 if bf16).
// ---------------------------------------------------------------------------
__global__ void detect_kernel(const unsigned* __restrict__ x, int* __restrict__ flag) {
    __shared__ int cnt;
    if (threadIdx.x == 0) cnt = 0;
    __syncthreads();
    int c = 0;
    for (int i = threadIdx.x; i < 4096; i += 256) {
        const unsigned w = x[i];
        const unsigned e = (w >> 7) & 0xFF;
        if (e >= 105 && e <= 140) ++c;
    }
    atomicAdd(&cnt, c);
    __syncthreads();
    if (threadIdx.x == 0) flag[0] = (cnt > 2300) ? 1 : 0;
}

// ---------------------------------------------------------------------------
// Elementwise cast (dyn f32/bf16 -> bf16), 8 elems/thread.
// ---------------------------------------------------------------------------
__global__ __launch_bounds__(256) void cast_kernel(
    const void* __restrict__ in, u16* __restrict__ out, int n, const int* __restrict__ flagp)
{
    const int fl = flagp[0];
    const int i0 = (blockIdx.x * 256 + threadIdx.x) * 8;
    if (i0 + 8 > n) return;
    u16x8 o;
    #pragma unroll
    for (int i = 0; i < 8; ++i) o[i] = f2b(dynload(in, (size_t)i0 + i, fl));
    *(u16x8*)(out + i0) = o;
}

// ---------------------------------------------------------------------------
// Transpose + cast: W[K][N] (dyn) -> W_T[N][K] (bf16). 32x32 LDS tiles.
// Rows [N, Ntot) are written as zeros (pad for gload_lds GEMM B-tiles).
// ---------------------------------------------------------------------------
__global__ __launch_bounds__(256) void tcast_kernel(
    const void* __restrict__ in, u16* __restrict__ out, int K, int N, int Ntot,
    const int* __restrict__ flagp)
{
    const int fl = flagp[0];
    __shared__ float sf[32][33];
    const int n0 = blockIdx.x * 32, k0 = blockIdx.y * 32;
    const int tx = threadIdx.x & 31, ty = threadIdx.x >> 5;
    const int cr = (n0 + tx < N) ? (n0 + tx) : (N - 1);   // clamped read col
    #pragma unroll
    for (int i = 0; i < 4; ++i)
        sf[ty + 8 * i][tx] = dynload(in, (size_t)(k0 + ty + 8 * i) * N + cr, fl);
    __syncthreads();
    #pragma unroll
    for (int i = 0; i < 4; ++i) {
        const int n = n0 + ty + 8 * i;
        if (n < Ntot) out[(size_t)n * K + k0 + tx] = (n < N) ? f2b(sf[tx][ty + 8 * i]) : (u16)0;
    }
}

// ---------------------------------------------------------------------------
// MFMA GEMM (m97 structure): C[M,N] = A[M,K] @ B[K,N], A row-major bf16,
// BT = B^T row-major bf16 [N][K] (rows padded so n-tiles are full 128).
// 128x128 tile, BK=32, 4 waves each 64x64 (4x4 of 16x16x32).
// Staging via global_load_lds width=16 into LINEAR (unpadded) LDS.
// ---------------------------------------------------------------------------
__device__ __forceinline__ void stc(u16* p, float v)  { *p = f2b(v); }
__device__ __forceinline__ void stc(float* p, float v){ *p = v; }

template <typename TC>
__global__ __launch_bounds__(256) void mfma_gemm(
    const u16* __restrict__ A, int lda,
    const u16* __restrict__ BT, int ldb,
    TC* __restrict__ Cm, int ldc,
    int M, int N, int K)
{
    __shared__ u16 As[128 * 32];   // linear [m][k], row = 64B
    __shared__ u16 Bs[128 * 32];   // linear [n][k]
    const int tid = threadIdx.x;
    const int m0 = blockIdx.y * 128, n0 = blockIdx.x * 128;
    const int w = tid >> 6, l = tid & 63;
    const int wm = (w >> 1) * 64, wn = (w & 1) * 64;
    const int lr = l & 15, lq = l >> 4;

    f32x4 acc[4][4];
    #pragma unroll
    for (int i = 0; i < 4; ++i)
        #pragma unroll
        for (int j = 0; j < 4; ++j) acc[i][j] = (f32x4){0.f, 0.f, 0.f, 0.f};

    // per-lane global source addresses matching the linear LDS order
    const int srow = w * 32 + (l >> 2);
    const int scol = (l & 3) * 8;
    const u16* ag = A  + (size_t)(m0 + srow) * lda + scol;
    const u16* bg = BT + (size_t)(n0 + srow) * ldb + scol;
    u16* as0 = &As[(w * 32) * 32];
    u16* as1 = &As[(w * 32 + 16) * 32];
    u16* bs0 = &Bs[(w * 32) * 32];
    u16* bs1 = &Bs[(w * 32 + 16) * 32];

    for (int k0 = 0; k0 < K; k0 += 32) {
        gload16(ag + k0,            as0);
        gload16(ag + 16 * lda + k0, as1);
        gload16(bg + k0,            bs0);
        gload16(bg + 16 * ldb + k0, bs1);
        __syncthreads();
        bfv8 af[4], bf[4];
        #pragma unroll
        for (int mi = 0; mi < 4; ++mi) af[mi] = *(const bfv8*)&As[(wm + mi * 16 + lr) * 32 + lq * 8];
        #pragma unroll
        for (int ni = 0; ni < 4; ++ni) bf[ni] = *(const bfv8*)&Bs[(wn + ni * 16 + lr) * 32 + lq * 8];
        #pragma unroll
        for (int mi = 0; mi < 4; ++mi)
            #pragma unroll
            for (int ni = 0; ni < 4; ++ni)
                acc[mi][ni] = __builtin_amdgcn_mfma_f32_16x16x32_bf16(af[mi], bf[ni], acc[mi][ni], 0, 0, 0);
        __syncthreads();
    }

    #pragma unroll
    for (int mi = 0; mi < 4; ++mi) {
        #pragma unroll
        for (int ni = 0; ni < 4; ++ni) {
            const int col = n0 + wn + ni * 16 + lr;
            if (col < N) {
                #pragma unroll
                for (int r = 0; r < 4; ++r) {
                    const int row = m0 + wm + mi * 16 + lq * 4 + r;
                    stc(&Cm[(size_t)row * ldc + col], acc[mi][ni][r]);
                }
            }
        }
    }
}

// ---------------------------------------------------------------------------
// Assemble q/k/v per (b,t): rope + rmsnorm for q,k; gated v with ve einsum.
// ---------------------------------------------------------------------------
__global__ __launch_bounds__(256) void assemble_kernel(
    const u16* __restrict__ down,      // [NT,1168] bf16
    const u16* __restrict__ qraw,      // [NT,2048] bf16
    const u16* __restrict__ kv,        // [NT,3072] bf16
    const void* __restrict__ ve,       // [NT,8192] dyn
    const void* __restrict__ cosg,     // [NT,32]   dyn
    const void* __restrict__ sing,     // [NT,32]   dyn
    u16* __restrict__ qo, u16* __restrict__ ko, u16* __restrict__ vo,
    const int* __restrict__ flagp)
{
    const int fl = flagp[0];
    const int bt = blockIdx.x;
    const int tid = threadIdx.x;
    __shared__ float cs[32], sn[32], kr[64];
    if (tid < 32) {
        cs[tid] = dynload(cosg, (size_t)bt * 32 + tid, fl);
        sn[tid] = dynload(sing, (size_t)bt * 32 + tid, fl);
    }
    __syncthreads();
    if (tid < 64) {
        const u16* rp = down + (size_t)bt * DCAT + 1024;
        const int d = tid;
        if (d < 32) kr[d] = b2f(rp[d]) * cs[d] + b2f(rp[d + 32]) * sn[d];
        else { const int r = d - 32; kr[d] = -b2f(rp[d - 32]) * sn[r] + b2f(rp[d]) * cs[r]; }
    }
    __syncthreads();

    const int h = tid >> 4;
    const int lane = tid & 15;
    const int d0 = lane * 8;

    // Q: rope on [64,128), rmsnorm over 128
    const u16* qr = qraw + (size_t)bt * Q_N + h * HD_;
    float vq[8];
    float ss = 0.f;
    #pragma unroll
    for (int i = 0; i < 8; ++i) {
        const int d = d0 + i;
        float xv = b2f(qr[d]);
        if (d >= 64) {
            if (d < 96) { const int r = d - 64; xv = xv * cs[r] + b2f(qr[d + 32]) * sn[r]; }
            else        { const int r = d - 96; xv = -b2f(qr[d - 32]) * sn[r] + xv * cs[r]; }
        }
        vq[i] = xv; ss += xv * xv;
    }
    #pragma unroll
    for (int off = 1; off < 16; off <<= 1) ss += __shfl_xor(ss, off);
    float rms = rsqrtf(ss * (1.f / 128.f) + EPS_);
    u16* qop = qo + (size_t)bt * Q_N + h * HD_ + d0;
    #pragma unroll
    for (int i = 0; i < 8; ++i) qop[i] = f2b(vq[i] * rms);

    // K: [k_nope(64) | roped k_rope(64)], rmsnorm over 128
    const u16* kvp = kv + (size_t)bt * KV_N + h * 192;
    float vk[8];
    ss = 0.f;
    #pragma unroll
    for (int i = 0; i < 8; ++i) {
        const int d = d0 + i;
        const float xv = (d < 64) ? b2f(kvp[d]) : kr[d - 64];
        vk[i] = xv; ss += xv * xv;
    }
    #pragma unroll
    for (int off = 1; off < 16; off <<= 1) ss += __shfl_xor(ss, off);
    rms = rsqrtf(ss * (1.f / 128.f) + EPS_);
    u16* kop = ko + (size_t)bt * Q_N + h * HD_ + d0;
    #pragma unroll
    for (int i = 0; i < 8; ++i) kop[i] = f2b(vk[i] * rms);

    // V: g0 * v + sum_m g[m+1] * ve[m]; gates = 2*sigmoid(down[1088 + h*5 + j])
    float g[5];
    #pragma unroll
    for (int j = 0; j < 5; ++j) {
        const float logit = b2f(down[(size_t)bt * DCAT + 1088 + h * 5 + j]);
        g[j] = 2.f / (1.f + expf(-logit));
    }
    const u16* vp = kvp + 64;
    const size_t vebase = (size_t)bt * 8192 + h * HD_;
    u16* vop = vo + (size_t)bt * Q_N + h * HD_ + d0;
    #pragma unroll
    for (int i = 0; i < 8; ++i) {
        const int d = d0 + i;
        float val = g[0] * b2f(vp[d]);
        #pragma unroll
        for (int m = 0; m < 4; ++m) val += g[1 + m] * dynload(ve, vebase + m * 2048 + d, fl);
        vop[i] = f2b(val);
    }
}

// ---------------------------------------------------------------------------
// V transpose: vn [b][t][h][d] -> vt [(b,h)][d][t]   (bf16, 64x64 tiles)
// ---------------------------------------------------------------------------
__global__ __launch_bounds__(256) void vtrans_kernel(
    const u16* __restrict__ vn, u16* __restrict__ vt)
{
    __shared__ u16 s[64][72];
    const int t0 = blockIdx.x * 64;
    const int d0 = blockIdx.y * 64;
    const int bh = blockIdx.z;
    const int tid = threadIdx.x;
    {
        const int tt = tid >> 2, seg = tid & 3;
        const u16* p = vn + ((size_t)((bh >> 4) * T_) + t0 + tt) * 2048 + (bh & 15) * 128 + d0 + seg * 16;
        u16x8 v0 = *(const u16x8*)(p);
        u16x8 v1 = *(const u16x8*)(p + 8);
        *(u16x8*)&s[tt][seg * 16]     = v0;
        *(u16x8*)&s[tt][seg * 16 + 8] = v1;
    }
    __syncthreads();
    {
        const int dd = tid >> 2, tseg = tid & 3;
        u16* q = vt + ((size_t)(bh * 128) + d0 + dd) * T_ + t0 + tseg * 16;
        #pragma unroll
        for (int g = 0; g < 2; ++g) {
            u16x8 o;
            #pragma unroll
            for (int i = 0; i < 8; ++i) o[i] = s[tseg * 16 + g * 8 + i][dd];
            *(u16x8*)(q + g * 8) = o;
        }
    }
}

// ---------------------------------------------------------------------------
// MFMA flash attention v3: split-K for load balance. 256 threads (4 waves),
// 128 q-rows/block, 64-key tiles. Fixed-max softmax (v2) makes partials
// purely additive: O = sum_c O_c, l = sum_c l_c -> trivial combine.
//
// Grid = 768 blocks, blockIdx.x:
//   [0,512):  mb in 8..15 split into 2 key-chunks (<=16 tiles each).
//             c = bit0; r = i>>1: mb = 15-(r&7), h = (r>>3)&15, b = r>>7.
//             Writes f32 partial O[i][128][128] and l[i][128].
//   [512,768): mb in 0..7 single-chunk (<=16 tiles), writes y directly.
// Long chunks have low blockIdx -> dispatch first; 768 blocks on ~512
// co-resident slots -> HW refill keeps CUs busy (fixes 7.4% occupancy).
// ---------------------------------------------------------------------------
__global__ __launch_bounds__(256) void attn_mfma(
    const u16* __restrict__ qn, const u16* __restrict__ kn,
    const u16* __restrict__ vt, u16* __restrict__ yb,
    float* __restrict__ po, float* __restrict__ pl,
    const int* __restrict__ wptr)
{
    __shared__ u16 Ks[64][136];      // K tile row-major [key][d]
    __shared__ u16 VTs[144][72];     // V^T tile [d][key]; rows 128..143 = ones-block
    __shared__ u16 Ps[4][32][72];    // per-wave P round-trip [qrow][key]

    const int i = (int)blockIdx.x;
    int b, h, mb, c;
    bool split;
    if (i < 512) {
        split = true; c = i & 1;
        const int r = i >> 1;
        mb = 15 - (r & 7); h = (r >> 3) & 15; b = r >> 7;
    } else {
        split = false; c = 0;
        const int j = i - 512;
        mb = 7 - (j & 7); h = (j >> 3) & 15; b = j >> 7;
    }
    const int m0 = mb * 128;
    const int W = wptr[0];
    const int tid = threadIdx.x;
    const int w = tid >> 6, l = tid & 63;
    const int lr = l & 15, lq = l >> 4;
    const int qr0 = m0 + w * 32;

    // Q fragments: 2 row-tiles x 4 k-slices
    bfv8 qf[2][4];
    #pragma unroll
    for (int mi = 0; mi < 2; ++mi) {
        const u16* qp = qn + ((size_t)(b * T_) + qr0 + mi * 16 + lr) * 2048 + h * 128 + lq * 8;
        #pragma unroll
        for (int kk = 0; kk < 4; ++kk) qf[mi][kk] = *(const bfv8*)(qp + kk * 32);
    }

    f32x4 oacc[2][8];
    f32x4 lacc[2];
    #pragma unroll
    for (int mi = 0; mi < 2; ++mi) {
        lacc[mi] = (f32x4){0.f, 0.f, 0.f, 0.f};
        #pragma unroll
        for (int od = 0; od < 8; ++od) oacc[mi][od] = (f32x4){0.f, 0.f, 0.f, 0.f};
    }

    // static ones-block: VTs row 128 = 1.0, rows 129..143 = 0 (cols 0..63)
    {
        const int rr = 128 + (tid >> 4), cc = (tid & 15) * 4;
        const u16 v = (tid >> 4) == 0 ? (u16)0x3F80 : (u16)0;
        VTs[rr][cc] = v; VTs[rr][cc + 1] = v; VTs[rr][cc + 2] = v; VTs[rr][cc + 3] = v;
    }

    // staging indices (256 threads, 64B contiguous per thread)
    const int kkey = tid >> 2, kq = tid & 3;     // K: 64 rows x 4 segs of 32 u16
    const int vd = tid >> 1, vh2 = tid & 1;      // V: 128 rows x 2 segs of 32 u16

    int ns = m0 - W; if (ns < 0) ns = 0; ns &= ~63;
    const int ne = m0 + 64;                      // inclusive last tile start

    // chunk sub-range [n_lo, n_hi] (inclusive tile starts)
    int n_lo = ns, n_hi = ne;
    if (split) {
        const int nt = ((ne - ns) >> 6) + 1;     // total tiles (>=2)
        const int h0 = (nt + 1) >> 1;            // tiles in chunk 0
        if (c == 0) n_hi = ns + (h0 - 1) * 64;
        else        n_lo = ns + h0 * 64;
        if (n_lo > n_hi) { n_lo = ns; n_hi = ns - 64; }   // paranoia: empty chunk
    }

    const u16* kbase = kn + ((size_t)(b * T_) + kkey) * 2048 + h * 128 + kq * 32;
    const u16* vbase = vt + ((size_t)(b * H_ + h) * 128 + vd) * T_ + vh2 * 32;

    // prologue: prefetch first tile into registers (T14)
    u16x8 pk[4], pv[4];
    {
        const u16* kp = kbase + (size_t)n_lo * 2048;
        const u16* vp = vbase + n_lo;
        #pragma unroll
        for (int s = 0; s < 4; ++s) pk[s] = *(const u16x8*)(kp + s * 8);
        #pragma unroll
        for (int s = 0; s < 4; ++s) pv[s] = *(const u16x8*)(vp + s * 8);
    }

    for (int n0 = n_lo; n0 <= n_hi; n0 += 64) {
        {   // write previously-fetched tile to LDS
            u16* kd = &Ks[kkey][kq * 32];
            #pragma unroll
            for (int s = 0; s < 4; ++s) *(u16x8*)(kd + s * 8) = pk[s];
            u16* vdst = &VTs[vd][vh2 * 32];
            #pragma unroll
            for (int s = 0; s < 4; ++s) *(u16x8*)(vdst + s * 8) = pv[s];
        }
        __syncthreads();

        // issue next tile's loads; latency hides under compute below
        if (n0 < n_hi) {
            const u16* kp = kbase + (size_t)(n0 + 64) * 2048;
            const u16* vp = vbase + (n0 + 64);
            #pragma unroll
            for (int s = 0; s < 4; ++s) pk[s] = *(const u16x8*)(kp + s * 8);
            #pragma unroll
            for (int s = 0; s < 4; ++s) pv[s] = *(const u16x8*)(vp + s * 8);
        }

        // per-wave early-out on fully-masked tiles (barriers stay uniform)
        const bool active = (n0 <= qr0 + 31) && (n0 + 63 >= qr0 - W);
        if (active) {
            // S = Q K^T for both row-tiles (K fragments shared)
            f32x4 s0[4], s1[4];
            #pragma unroll
            for (int f = 0; f < 4; ++f) {
                f32x4 a0 = (f32x4){0.f, 0.f, 0.f, 0.f};
                f32x4 a1 = (f32x4){0.f, 0.f, 0.f, 0.f};
                #pragma unroll
                for (int kk = 0; kk < 4; ++kk) {
                    bfv8 kf = *(const bfv8*)&Ks[f * 16 + lr][kk * 32 + lq * 8];
                    a0 = __builtin_amdgcn_mfma_f32_16x16x32_bf16(qf[0][kk], kf, a0, 0, 0, 0);
                    a1 = __builtin_amdgcn_mfma_f32_16x16x32_bf16(qf[1][kk], kf, a1, 0, 0, 0);
                }
                s0[f] = a0; s1[f] = a1;
            }

            if ((n0 + 63 > qr0) || (qr0 + 31 - n0 > W)) {
                #pragma unroll
                for (int f = 0; f < 4; ++f) {
                    const int si = n0 + f * 16 + lr;
                    #pragma unroll
                    for (int r = 0; r < 4; ++r) {
                        const int t0i = qr0 + lq * 4 + r;
                        const int t1i = t0i + 16;
                        if (si > t0i || t0i - si > W) s0[f][r] = -1e30f;
                        if (si > t1i || t1i - si > W) s1[f][r] = -1e30f;
                    }
                }
            }

            // fixed-max exponent + P -> LDS (Ps[w] wave-private, no barrier)
            #pragma unroll
            for (int f = 0; f < 4; ++f)
                #pragma unroll
                for (int r = 0; r < 4; ++r) {
                    const float p0 = exp2f(s0[f][r] * CEXP - SMAXS);
                    const float p1 = exp2f(s1[f][r] * CEXP - SMAXS);
                    Ps[w][lq * 4 + r][f * 16 + lr]      = f2b(p0);
                    Ps[w][16 + lq * 4 + r][f * 16 + lr] = f2b(p1);
                }

            // O += P V ; l += P 1 (ones-block)
            bfv8 pf0[2], pf1[2];
            #pragma unroll
            for (int kk2 = 0; kk2 < 2; ++kk2) {
                pf0[kk2] = *(const bfv8*)&Ps[w][lr][kk2 * 32 + lq * 8];
                pf1[kk2] = *(const bfv8*)&Ps[w][16 + lr][kk2 * 32 + lq * 8];
            }
            #pragma unroll
            for (int kk2 = 0; kk2 < 2; ++kk2) {
                #pragma unroll
                for (int od = 0; od < 8; ++od) {
                    bfv8 vf = *(const bfv8*)&VTs[od * 16 + lr][kk2 * 32 + lq * 8];
                    oacc[0][od] = __builtin_amdgcn_mfma_f32_16x16x32_bf16(pf0[kk2], vf, oacc[0][od], 0, 0, 0);
                    oacc[1][od] = __builtin_amdgcn_mfma_f32_16x16x32_bf16(pf1[kk2], vf, oacc[1][od], 0, 0, 0);
                }
                bfv8 vf1 = *(const bfv8*)&VTs[128 + lr][kk2 * 32 + lq * 8];
                lacc[0] = __builtin_amdgcn_mfma_f32_16x16x32_bf16(pf0[kk2], vf1, lacc[0], 0, 0, 0);
                lacc[1] = __builtin_amdgcn_mfma_f32_16x16x32_bf16(pf1[kk2], vf1, lacc[1], 0, 0, 0);
            }
        }
        __syncthreads();
    }

    if (!split) {
        // epilogue: l in lanes lr==0; broadcast + divide, write bf16 y
        #pragma unroll
        for (int mi = 0; mi < 2; ++mi) {
            float linv[4];
            #pragma unroll
            for (int r = 0; r < 4; ++r) {
                const float lv = __shfl(lacc[mi][r], l & 48);
                linv[r] = 1.f / lv;
            }
            #pragma unroll
            for (int od = 0; od < 8; ++od)
                #pragma unroll
                for (int r = 0; r < 4; ++r) {
                    const size_t idx = ((size_t)(b * T_) + qr0 + mi * 16 + lq * 4 + r) * 2048
                                     + h * 128 + od * 16 + lr;
                    yb[idx] = f2b(oacc[mi][od][r] * linv[r]);
                }
        }
    } else {
        // write f32 partial O and l; combined later
        float* op = po + (size_t)i * 16384;
        #pragma unroll
        for (int mi = 0; mi < 2; ++mi) {
            #pragma unroll
            for (int od = 0; od < 8; ++od)
                #pragma unroll
                for (int r = 0; r < 4; ++r)
                    op[(w * 32 + mi * 16 + lq * 4 + r) * 128 + od * 16 + lr] = oacc[mi][od][r];
            if (lr == 0) {
                #pragma unroll
                for (int r = 0; r < 4; ++r)
                    pl[(size_t)i * 128 + w * 32 + mi * 16 + lq * 4 + r] = lacc[mi][r];
            }
        }
    }
}

// ---------------------------------------------------------------------------
// Combine split-K partials for mb 8..15: y = (O_a + O_b) / (l_a + l_b).
// Grid (8, 16, 2) = (mbi, h, b), 256 threads; thread t: row t>>1, col half t&1.
// ---------------------------------------------------------------------------
__global__ __launch_bounds__(256) void attn_combine(
    const float* __restrict__ po, const float* __restrict__ pl, u16* __restrict__ yb)
{
    const int mbi = blockIdx.x, h = blockIdx.y, b = blockIdx.z;
    const int r2 = (b << 7) | (h << 3) | mbi;
    const int mb = 15 - mbi;
    const int t = threadIdx.x;
    const int row = t >> 1;
    const int ch = (t & 1) * 64;
    const float la = pl[(size_t)(r2 * 2) * 128 + row];
    const float lb = pl[(size_t)(r2 * 2 + 1) * 128 + row];
    const float linv = 1.f / (la + lb);
    const float* oa = po + (size_t)(r2 * 2) * 16384 + row * 128 + ch;
    const float* ob = oa + 16384;
    u16* yp = yb + ((size_t)(b * T_) + mb * 128 + row) * 2048 + h * 128 + ch;
    #pragma unroll
    for (int g = 0; g < 8; ++g) {
        const f32x4 a0 = *(const f32x4*)(oa + g * 8);
        const f32x4 a1 = *(const f32x4*)(oa + g * 8 + 4);
        const f32x4 b0 = *(const f32x4*)(ob + g * 8);
        const f32x4 b1 = *(const f32x4*)(ob + g * 8 + 4);
        u16x8 o;
        #pragma unroll
        for (int k = 0; k < 4; ++k) o[k]     = f2b((a0[k] + b0[k]) * linv);
        #pragma unroll
        for (int k = 0; k < 4; ++k) o[4 + k] = f2b((a1[k] + b1[k]) * linv);
        *(u16x8*)(yp + g * 8) = o;
    }
}

// ---------------------------------------------------------------------------
extern "C" void kernel_launch(void* const* d_in, const int* in_sizes, int n_in,
                              void* d_out, int out_size, void* d_ws, size_t ws_size,
                              hipStream_t stream)
{
    const void* x      = d_in[0];
    const void* ve     = d_in[1];
    const void* cosg   = d_in[2];
    const void* sing   = d_in[3];
    const void* w_down = d_in[4];
    const void* w_ukv  = d_in[5];
    const void* w_uq   = d_in[6];
    const void* w_gate = d_in[7];
    const void* w_proj = d_in[8];
    const int*  wsz    = (const int*)d_in[9];
    float* out = (float*)d_out;

    // workspace (~121 MB with aliasing)
    char* p = (char*)d_ws;
    u16* xbf    = (u16*)p; p += (size_t)NT_ * C_ * 2;          // reused as qn
    u16* wcatT  = (u16*)p; p += (size_t)DCATP * C_ * 2;        // [w_down|w_gate|0pad]^T
    u16* wukvT  = (u16*)p; p += (size_t)KV_N * 512 * 2;
    u16* wuqT   = (u16*)p; p += (size_t)Q_N * 512 * 2;
    u16* wpT    = (u16*)p; p += (size_t)C_ * C_ * 2;
    u16* downb  = (u16*)p; p += (size_t)NT_ * DCAT * 2;
    u16* kvb    = (u16*)p; p += (size_t)NT_ * KV_N * 2;
    u16* qraw   = (u16*)p; p += (size_t)NT_ * Q_N * 2;         // reused as vtb
    u16* kn     = (u16*)p; p += (size_t)NT_ * Q_N * 2;
    u16* vn     = (u16*)p; p += (size_t)NT_ * Q_N * 2;         // reused as ybf
    int* flag   = (int*)p; p += 256;
    u16* qn  = xbf;    // x_bf dead after down GEMM
    u16* vtb = qraw;   // qraw dead after assemble
    u16* ybf = vn;     // vn dead after vtrans (attn reads vtb)
    // split-K partials alias downb+kvb (both dead after assemble):
    //   po: 512 * 128 * 128 f32 = 33.55 MB, pl: 512 * 128 f32 = 0.26 MB
    //   downb+kvb region = 34.73 MB  -> fits
    float* attn_po = (float*)downb;
    float* attn_pl = (float*)((char*)downb + (size_t)512 * 16384 * 4);

    dim3 blk(256);
    detect_kernel<<<1, blk, 0, stream>>>((const unsigned*)x, flag);
    cast_kernel<<<dim3(NT_ * C_ / (256 * 8)), blk, 0, stream>>>(x, xbf, NT_ * C_, flag);
    tcast_kernel<<<dim3(DOWN_N / 32, C_ / 32), blk, 0, stream>>>(w_down, wcatT, C_, DOWN_N, DOWN_N, flag);
    // gate cols + zero-pad rows up to DCATP (192 rows total from offset 1088)
    tcast_kernel<<<dim3((DCATP - DOWN_N) / 32, C_ / 32), blk, 0, stream>>>(
        w_gate, wcatT + (size_t)DOWN_N * C_, C_, 80, DCATP - DOWN_N, flag);
    tcast_kernel<<<dim3(KV_N / 32, 512 / 32), blk, 0, stream>>>(w_ukv, wukvT, 512, KV_N, KV_N, flag);
    tcast_kernel<<<dim3(Q_N / 32, 512 / 32), blk, 0, stream>>>(w_uq, wuqT, 512, Q_N, Q_N, flag);
    tcast_kernel<<<dim3(C_ / 32, C_ / 32), blk, 0, stream>>>(w_proj, wpT, C_, C_, C_, flag);

    // down+gates = x @ [w_down|w_gate] -> bf16 [4096,1168] (B padded to 1280 rows)
    mfma_gemm<u16><<<dim3(DCATP / 128, NT_ / 128), blk, 0, stream>>>(
        xbf, C_, wcatT, C_, downb, DCAT, NT_, DCAT, C_);
    // kv = c_kv @ w_ukv -> bf16 [4096,3072]
    mfma_gemm<u16><<<dim3(KV_N / 128, NT_ / 128), blk, 0, stream>>>(
        downb, DCAT, wukvT, 512, kvb, KV_N, NT_, KV_N, 512);
    // q_raw = c_q @ w_uq -> bf16 [4096,2048]
    mfma_gemm<u16><<<dim3(Q_N / 128, NT_ / 128), blk, 0, stream>>>(
        downb + 512, DCAT, wuqT, 512, qraw, Q_N, NT_, Q_N, 512);
    // assemble q/k/v (incl. gate sigmoid from down logits)
    assemble_kernel<<<dim3(NT_), blk, 0, stream>>>(
        downb, qraw, kvb, ve, cosg, sing, qn, kn, vn, flag);
    // v transpose to [(b,h)][d][t]
    vtrans_kernel<<<dim3(T_ / 64, 2, B_ * H_), blk, 0, stream>>>(vn, vtb);
    // flash attention (split-K, 768 blocks) -> y bf16 + f32 partials
    attn_mfma<<<dim3(768), dim3(256), 0, stream>>>(qn, kn, vtb, ybf, attn_po, attn_pl, wsz);
    // combine partials for mb 8..15
    attn_combine<<<dim3(8, 16, 2), blk, 0, stream>>>(attn_po, attn_pl, ybf);
    // out = y @ w_proj -> f32
    mfma_gemm<float><<<dim3(Q_N / 128, NT_ / 128), blk, 0, stream>>>(
        ybf, Q_N, wpT, C_, out, C_, NT_, C_, Q_N);
}

// Round 7
// 577.699 us; speedup vs baseline: 1.1724x; 1.1410x over previous
//
#include <hip/hip_runtime.h>

typedef unsigned short u16;
typedef __bf16 bfv8 __attribute__((ext_vector_type(8)));
typedef float f32x4 __attribute__((ext_vector_type(4)));
typedef u16 u16x8 __attribute__((ext_vector_type(8)));

#define B_      2
#define T_      2048
#define C_      2048
#define H_      16
#define HD_     128
#define NT_     (B_ * T_)
#define DOWN_N  1088
#define DCAT    1168   // 1088 (down) + 80 (gate logits)
#define DCATP   1280   // DCAT padded to 128 multiple (zero rows) for gload_lds GEMM
#define KV_N    3072
#define Q_N     2048
#define EPS_    1.1920929e-07f
// softmax scale (1/sqrt(128)) * log2(e), for exp2-domain online softmax
#define CEXP    0.12751879524580262f
// fixed softmax "max": q,k rmsnormed -> |s|*CEXP <= 128*CEXP = 16.33 (+bf16 slop)
#define SMAXS   16.6f

__device__ __forceinline__ float b2f(u16 u) {
    union { unsigned u; float f; } c; c.u = ((unsigned)u) << 16; return c.f;
}
__device__ __forceinline__ u16 f2b(float f) {
    union { float f; unsigned u; } c; c.f = f;
    return (u16)((c.u + 0x7FFFu + ((c.u >> 16) & 1u)) >> 16);
}
__device__ __forceinline__ float dynload(const void* p, size_t i, int bf) {
    if (bf) return b2f(((const u16*)p)[i]);
    return ((const float*)p)[i];
}

// async global->LDS, 16B per lane (wave-uniform LDS base + lane*16)
__device__ __forceinline__ void gload16(const u16* g, u16* l) {
    __builtin_amdgcn_global_load_lds(
        (const __attribute__((address_space(1))) void*)g,
        (__attribute__((address_space(3))) void*)l,
        16, 0, 0);
}

// ---------------------------------------------------------------------------
// Input dtype detector (writes flag[0] = 1 if bf16).
// ---------------------------------------------------------------------------
__global__ void detect_kernel(const unsigned* __restrict__ x, int* __restrict__ flag) {
    __shared__ int cnt;
    if (threadIdx.x == 0) cnt = 0;
    __syncthreads();
    int c = 0;
    for (int i = threadIdx.x; i < 4096; i += 256) {
        const unsigned w = x[i];
        const unsigned e = (w >> 7) & 0xFF;
        if (e >= 105 && e <= 140) ++c;
    }
    atomicAdd(&cnt, c);
    __syncthreads();
    if (threadIdx.x == 0) flag[0] = (cnt > 2300) ? 1 : 0;
}

// ---------------------------------------------------------------------------
// Elementwise cast (dyn f32/bf16 -> bf16), 8 elems/thread, VECTORIZED (G13).
// ---------------------------------------------------------------------------
__global__ __launch_bounds__(256) void cast_kernel(
    const void* __restrict__ in, u16* __restrict__ out, int n, const int* __restrict__ flagp)
{
    const int fl = flagp[0];
    const int i0 = (blockIdx.x * 256 + threadIdx.x) * 8;
    if (i0 + 8 > n) return;
    u16x8 o;
    if (fl) {
        o = *(const u16x8*)((const u16*)in + i0);
    } else {
        const f32x4 a = *(const f32x4*)((const float*)in + i0);
        const f32x4 b = *(const f32x4*)((const float*)in + i0 + 4);
        #pragma unroll
        for (int i = 0; i < 4; ++i) { o[i] = f2b(a[i]); o[4 + i] = f2b(b[i]); }
    }
    *(u16x8*)(out + i0) = o;
}

// ---------------------------------------------------------------------------
// Transpose + cast: W[K][N] (dyn) -> W_T[N][K] (bf16). 32x32 LDS tiles.
// Rows [N, Ntot) are written as zeros (pad for gload_lds GEMM B-tiles).
// ---------------------------------------------------------------------------
__global__ __launch_bounds__(256) void tcast_kernel(
    const void* __restrict__ in, u16* __restrict__ out, int K, int N, int Ntot,
    const int* __restrict__ flagp)
{
    const int fl = flagp[0];
    __shared__ float sf[32][33];
    const int n0 = blockIdx.x * 32, k0 = blockIdx.y * 32;
    const int tx = threadIdx.x & 31, ty = threadIdx.x >> 5;
    const int cr = (n0 + tx < N) ? (n0 + tx) : (N - 1);   // clamped read col
    #pragma unroll
    for (int i = 0; i < 4; ++i)
        sf[ty + 8 * i][tx] = dynload(in, (size_t)(k0 + ty + 8 * i) * N + cr, fl);
    __syncthreads();
    #pragma unroll
    for (int i = 0; i < 4; ++i) {
        const int n = n0 + ty + 8 * i;
        if (n < Ntot) out[(size_t)n * K + k0 + tx] = (n < N) ? f2b(sf[tx][ty + 8 * i]) : (u16)0;
    }
}

// ---------------------------------------------------------------------------
// MFMA GEMM (m97 structure): C[M,N] = A[M,K] @ B[K,N], A row-major bf16,
// BT = B^T row-major bf16 [N][K] (rows padded so n-tiles are full 128).
// 128x128 tile, BK=32, 4 waves each 64x64 (4x4 of 16x16x32).
// Staging via global_load_lds width=16 into LINEAR (unpadded) LDS.
// ---------------------------------------------------------------------------
__device__ __forceinline__ void stc(u16* p, float v)  { *p = f2b(v); }
__device__ __forceinline__ void stc(float* p, float v){ *p = v; }

template <typename TC>
__global__ __launch_bounds__(256) void mfma_gemm(
    const u16* __restrict__ A, int lda,
    const u16* __restrict__ BT, int ldb,
    TC* __restrict__ Cm, int ldc,
    int M, int N, int K)
{
    __shared__ u16 As[128 * 32];   // linear [m][k], row = 64B
    __shared__ u16 Bs[128 * 32];   // linear [n][k]
    const int tid = threadIdx.x;
    const int m0 = blockIdx.y * 128, n0 = blockIdx.x * 128;
    const int w = tid >> 6, l = tid & 63;
    const int wm = (w >> 1) * 64, wn = (w & 1) * 64;
    const int lr = l & 15, lq = l >> 4;

    f32x4 acc[4][4];
    #pragma unroll
    for (int i = 0; i < 4; ++i)
        #pragma unroll
        for (int j = 0; j < 4; ++j) acc[i][j] = (f32x4){0.f, 0.f, 0.f, 0.f};

    // per-lane global source addresses matching the linear LDS order
    const int srow = w * 32 + (l >> 2);
    const int scol = (l & 3) * 8;
    const u16* ag = A  + (size_t)(m0 + srow) * lda + scol;
    const u16* bg = BT + (size_t)(n0 + srow) * ldb + scol;
    u16* as0 = &As[(w * 32) * 32];
    u16* as1 = &As[(w * 32 + 16) * 32];
    u16* bs0 = &Bs[(w * 32) * 32];
    u16* bs1 = &Bs[(w * 32 + 16) * 32];

    for (int k0 = 0; k0 < K; k0 += 32) {
        gload16(ag + k0,            as0);
        gload16(ag + 16 * lda + k0, as1);
        gload16(bg + k0,            bs0);
        gload16(bg + 16 * ldb + k0, bs1);
        __syncthreads();
        bfv8 af[4], bf[4];
        #pragma unroll
        for (int mi = 0; mi < 4; ++mi) af[mi] = *(const bfv8*)&As[(wm + mi * 16 + lr) * 32 + lq * 8];
        #pragma unroll
        for (int ni = 0; ni < 4; ++ni) bf[ni] = *(const bfv8*)&Bs[(wn + ni * 16 + lr) * 32 + lq * 8];
        #pragma unroll
        for (int mi = 0; mi < 4; ++mi)
            #pragma unroll
            for (int ni = 0; ni < 4; ++ni)
                acc[mi][ni] = __builtin_amdgcn_mfma_f32_16x16x32_bf16(af[mi], bf[ni], acc[mi][ni], 0, 0, 0);
        __syncthreads();
    }

    #pragma unroll
    for (int mi = 0; mi < 4; ++mi) {
        #pragma unroll
        for (int ni = 0; ni < 4; ++ni) {
            const int col = n0 + wn + ni * 16 + lr;
            if (col < N) {
                #pragma unroll
                for (int r = 0; r < 4; ++r) {
                    const int row = m0 + wm + mi * 16 + lq * 4 + r;
                    stc(&Cm[(size_t)row * ldc + col], acc[mi][ni][r]);
                }
            }
        }
    }
}

// ---------------------------------------------------------------------------
// Assemble q/k/v per (b,t), VECTORIZED (G13): uniform dtype branch, u16x8 /
// f32x4 loads, u16x8 stores. Rope partner chunk for d0>=64 is qr[d0^32].
// ---------------------------------------------------------------------------
__global__ __launch_bounds__(256) void assemble_kernel(
    const u16* __restrict__ down,      // [NT,1168] bf16
    const u16* __restrict__ qraw,      // [NT,2048] bf16
    const u16* __restrict__ kv,        // [NT,3072] bf16
    const void* __restrict__ ve,       // [NT,8192] dyn
    const void* __restrict__ cosg,     // [NT,32]   dyn
    const void* __restrict__ sing,     // [NT,32]   dyn
    u16* __restrict__ qo, u16* __restrict__ ko, u16* __restrict__ vo,
    const int* __restrict__ flagp)
{
    const int fl = flagp[0];
    const int bt = blockIdx.x;
    const int tid = threadIdx.x;
    __shared__ float cs[32], sn[32], kr[64];
    if (tid < 32) {
        cs[tid] = dynload(cosg, (size_t)bt * 32 + tid, fl);
        sn[tid] = dynload(sing, (size_t)bt * 32 + tid, fl);
    }
    __syncthreads();
    if (tid < 64) {
        const u16* rp = down + (size_t)bt * DCAT + 1024;
        const int d = tid;
        if (d < 32) kr[d] = b2f(rp[d]) * cs[d] + b2f(rp[d + 32]) * sn[d];
        else { const int r = d - 32; kr[d] = -b2f(rp[d - 32]) * sn[r] + b2f(rp[d]) * cs[r]; }
    }
    __syncthreads();

    const int h = tid >> 4;
    const int lane = tid & 15;
    const int d0 = lane * 8;

    // ---- Q: rope on [64,128), rmsnorm over 128 --------------------------
    const u16* qr = qraw + (size_t)bt * Q_N + h * HD_;
    const u16x8 qown = *(const u16x8*)(qr + d0);
    float vq[8];
    if (d0 < 64) {
        #pragma unroll
        for (int i = 0; i < 8; ++i) vq[i] = b2f(qown[i]);
    } else {
        const u16x8 qpar = *(const u16x8*)(qr + (d0 ^ 32));
        if (d0 < 96) {
            #pragma unroll
            for (int i = 0; i < 8; ++i) {
                const int r = d0 + i - 64;
                vq[i] = b2f(qown[i]) * cs[r] + b2f(qpar[i]) * sn[r];
            }
        } else {
            #pragma unroll
            for (int i = 0; i < 8; ++i) {
                const int r = d0 + i - 96;
                vq[i] = -b2f(qpar[i]) * sn[r] + b2f(qown[i]) * cs[r];
            }
        }
    }
    float ss = 0.f;
    #pragma unroll
    for (int i = 0; i < 8; ++i) ss += vq[i] * vq[i];
    #pragma unroll
    for (int off = 1; off < 16; off <<= 1) ss += __shfl_xor(ss, off);
    float rms = rsqrtf(ss * (1.f / 128.f) + EPS_);
    {
        u16x8 o;
        #pragma unroll
        for (int i = 0; i < 8; ++i) o[i] = f2b(vq[i] * rms);
        *(u16x8*)(qo + (size_t)bt * Q_N + h * HD_ + d0) = o;
    }

    // ---- K: [k_nope(64) | roped k_rope(64)], rmsnorm over 128 -----------
    const u16* kvp = kv + (size_t)bt * KV_N + h * 192;
    float vk[8];
    if (d0 < 64) {
        const u16x8 kown = *(const u16x8*)(kvp + d0);
        #pragma unroll
        for (int i = 0; i < 8; ++i) vk[i] = b2f(kown[i]);
    } else {
        #pragma unroll
        for (int i = 0; i < 8; ++i) vk[i] = kr[d0 - 64 + i];
    }
    ss = 0.f;
    #pragma unroll
    for (int i = 0; i < 8; ++i) ss += vk[i] * vk[i];
    #pragma unroll
    for (int off = 1; off < 16; off <<= 1) ss += __shfl_xor(ss, off);
    rms = rsqrtf(ss * (1.f / 128.f) + EPS_);
    {
        u16x8 o;
        #pragma unroll
        for (int i = 0; i < 8; ++i) o[i] = f2b(vk[i] * rms);
        *(u16x8*)(ko + (size_t)bt * Q_N + h * HD_ + d0) = o;
    }

    // ---- V: g0 * v + sum_m g[m+1] * ve[m] -------------------------------
    float g[5];
    #pragma unroll
    for (int j = 0; j < 5; ++j) {
        const float logit = b2f(down[(size_t)bt * DCAT + 1088 + h * 5 + j]);
        g[j] = 2.f / (1.f + expf(-logit));
    }
    float vv[8];
    {
        const u16x8 vown = *(const u16x8*)(kvp + 64 + d0);
        #pragma unroll
        for (int i = 0; i < 8; ++i) vv[i] = g[0] * b2f(vown[i]);
    }
    const size_t vebase = (size_t)bt * 8192 + h * HD_ + d0;
    if (fl) {
        const u16* vep = (const u16*)ve;
        #pragma unroll
        for (int m = 0; m < 4; ++m) {
            const u16x8 e = *(const u16x8*)(vep + vebase + m * 2048);
            #pragma unroll
            for (int i = 0; i < 8; ++i) vv[i] += g[1 + m] * b2f(e[i]);
        }
    } else {
        const float* vep = (const float*)ve;
        #pragma unroll
        for (int m = 0; m < 4; ++m) {
            const f32x4 e0 = *(const f32x4*)(vep + vebase + m * 2048);
            const f32x4 e1 = *(const f32x4*)(vep + vebase + m * 2048 + 4);
            #pragma unroll
            for (int i = 0; i < 4; ++i) {
                vv[i]     += g[1 + m] * e0[i];
                vv[4 + i] += g[1 + m] * e1[i];
            }
        }
    }
    {
        u16x8 o;
        #pragma unroll
        for (int i = 0; i < 8; ++i) o[i] = f2b(vv[i]);
        *(u16x8*)(vo + (size_t)bt * Q_N + h * HD_ + d0) = o;
    }
}

// ---------------------------------------------------------------------------
// V transpose: vn [b][t][h][d] -> vt [(b,h)][d][t]   (bf16, 64x64 tiles)
// ---------------------------------------------------------------------------
__global__ __launch_bounds__(256) void vtrans_kernel(
    const u16* __restrict__ vn, u16* __restrict__ vt)
{
    __shared__ u16 s[64][72];
    const int t0 = blockIdx.x * 64;
    const int d0 = blockIdx.y * 64;
    const int bh = blockIdx.z;
    const int tid = threadIdx.x;
    {
        const int tt = tid >> 2, seg = tid & 3;
        const u16* p = vn + ((size_t)((bh >> 4) * T_) + t0 + tt) * 2048 + (bh & 15) * 128 + d0 + seg * 16;
        u16x8 v0 = *(const u16x8*)(p);
        u16x8 v1 = *(const u16x8*)(p + 8);
        *(u16x8*)&s[tt][seg * 16]     = v0;
        *(u16x8*)&s[tt][seg * 16 + 8] = v1;
    }
    __syncthreads();
    {
        const int dd = tid >> 2, tseg = tid & 3;
        u16* q = vt + ((size_t)(bh * 128) + d0 + dd) * T_ + t0 + tseg * 16;
        #pragma unroll
        for (int g = 0; g < 2; ++g) {
            u16x8 o;
            #pragma unroll
            for (int i = 0; i < 8; ++i) o[i] = s[tseg * 16 + g * 8 + i][dd];
            *(u16x8*)(q + g * 8) = o;
        }
    }
}

// ---------------------------------------------------------------------------
// MFMA flash attention v3: split-K for load balance. 256 threads (4 waves),
// 128 q-rows/block, 64-key tiles. Fixed-max softmax makes partials purely
// additive: O = sum_c O_c, l = sum_c l_c -> trivial combine.
//
// Grid = 768 blocks, blockIdx.x:
//   [0,512):  mb in 8..15 split into 2 key-chunks (<=16 tiles each).
//   [512,768): mb in 0..7 single-chunk (<=16 tiles), writes y directly.
// ---------------------------------------------------------------------------
__global__ __launch_bounds__(256) void attn_mfma(
    const u16* __restrict__ qn, const u16* __restrict__ kn,
    const u16* __restrict__ vt, u16* __restrict__ yb,
    float* __restrict__ po, float* __restrict__ pl,
    const int* __restrict__ wptr)
{
    __shared__ u16 Ks[64][136];      // K tile row-major [key][d]
    __shared__ u16 VTs[144][72];     // V^T tile [d][key]; rows 128..143 = ones-block
    __shared__ u16 Ps[4][32][72];    // per-wave P round-trip [qrow][key]

    const int i = (int)blockIdx.x;
    int b, h, mb, c;
    bool split;
    if (i < 512) {
        split = true; c = i & 1;
        const int r = i >> 1;
        mb = 15 - (r & 7); h = (r >> 3) & 15; b = r >> 7;
    } else {
        split = false; c = 0;
        const int j = i - 512;
        mb = 7 - (j & 7); h = (j >> 3) & 15; b = j >> 7;
    }
    const int m0 = mb * 128;
    const int W = wptr[0];
    const int tid = threadIdx.x;
    const int w = tid >> 6, l = tid & 63;
    const int lr = l & 15, lq = l >> 4;
    const int qr0 = m0 + w * 32;

    // Q fragments: 2 row-tiles x 4 k-slices
    bfv8 qf[2][4];
    #pragma unroll
    for (int mi = 0; mi < 2; ++mi) {
        const u16* qp = qn + ((size_t)(b * T_) + qr0 + mi * 16 + lr) * 2048 + h * 128 + lq * 8;
        #pragma unroll
        for (int kk = 0; kk < 4; ++kk) qf[mi][kk] = *(const bfv8*)(qp + kk * 32);
    }

    f32x4 oacc[2][8];
    f32x4 lacc[2];
    #pragma unroll
    for (int mi = 0; mi < 2; ++mi) {
        lacc[mi] = (f32x4){0.f, 0.f, 0.f, 0.f};
        #pragma unroll
        for (int od = 0; od < 8; ++od) oacc[mi][od] = (f32x4){0.f, 0.f, 0.f, 0.f};
    }

    // static ones-block: VTs row 128 = 1.0, rows 129..143 = 0 (cols 0..63)
    {
        const int rr = 128 + (tid >> 4), cc = (tid & 15) * 4;
        const u16 v = (tid >> 4) == 0 ? (u16)0x3F80 : (u16)0;
        VTs[rr][cc] = v; VTs[rr][cc + 1] = v; VTs[rr][cc + 2] = v; VTs[rr][cc + 3] = v;
    }

    // staging indices (256 threads, 64B contiguous per thread)
    const int kkey = tid >> 2, kq = tid & 3;     // K: 64 rows x 4 segs of 32 u16
    const int vd = tid >> 1, vh2 = tid & 1;      // V: 128 rows x 2 segs of 32 u16

    int ns = m0 - W; if (ns < 0) ns = 0; ns &= ~63;
    const int ne = m0 + 64;                      // inclusive last tile start

    // chunk sub-range [n_lo, n_hi] (inclusive tile starts)
    int n_lo = ns, n_hi = ne;
    if (split) {
        const int nt = ((ne - ns) >> 6) + 1;     // total tiles (>=2)
        const int h0 = (nt + 1) >> 1;            // tiles in chunk 0
        if (c == 0) n_hi = ns + (h0 - 1) * 64;
        else        n_lo = ns + h0 * 64;
        if (n_lo > n_hi) { n_lo = ns; n_hi = ns - 64; }   // paranoia: empty chunk
    }

    const u16* kbase = kn + ((size_t)(b * T_) + kkey) * 2048 + h * 128 + kq * 32;
    const u16* vbase = vt + ((size_t)(b * H_ + h) * 128 + vd) * T_ + vh2 * 32;

    // prologue: prefetch first tile into registers (T14)
    u16x8 pk[4], pv[4];
    {
        const u16* kp = kbase + (size_t)n_lo * 2048;
        const u16* vp = vbase + n_lo;
        #pragma unroll
        for (int s = 0; s < 4; ++s) pk[s] = *(const u16x8*)(kp + s * 8);
        #pragma unroll
        for (int s = 0; s < 4; ++s) pv[s] = *(const u16x8*)(vp + s * 8);
    }

    for (int n0 = n_lo; n0 <= n_hi; n0 += 64) {
        {   // write previously-fetched tile to LDS
            u16* kd = &Ks[kkey][kq * 32];
            #pragma unroll
            for (int s = 0; s < 4; ++s) *(u16x8*)(kd + s * 8) = pk[s];
            u16* vdst = &VTs[vd][vh2 * 32];
            #pragma unroll
            for (int s = 0; s < 4; ++s) *(u16x8*)(vdst + s * 8) = pv[s];
        }
        __syncthreads();

        // issue next tile's loads; latency hides under compute below
        if (n0 < n_hi) {
            const u16* kp = kbase + (size_t)(n0 + 64) * 2048;
            const u16* vp = vbase + (n0 + 64);
            #pragma unroll
            for (int s = 0; s < 4; ++s) pk[s] = *(const u16x8*)(kp + s * 8);
            #pragma unroll
            for (int s = 0; s < 4; ++s) pv[s] = *(const u16x8*)(vp + s * 8);
        }

        // per-wave early-out on fully-masked tiles (barriers stay uniform)
        const bool active = (n0 <= qr0 + 31) && (n0 + 63 >= qr0 - W);
        if (active) {
            // S = Q K^T for both row-tiles (K fragments shared)
            f32x4 s0[4], s1[4];
            #pragma unroll
            for (int f = 0; f < 4; ++f) {
                f32x4 a0 = (f32x4){0.f, 0.f, 0.f, 0.f};
                f32x4 a1 = (f32x4){0.f, 0.f, 0.f, 0.f};
                #pragma unroll
                for (int kk = 0; kk < 4; ++kk) {
                    bfv8 kf = *(const bfv8*)&Ks[f * 16 + lr][kk * 32 + lq * 8];
                    a0 = __builtin_amdgcn_mfma_f32_16x16x32_bf16(qf[0][kk], kf, a0, 0, 0, 0);
                    a1 = __builtin_amdgcn_mfma_f32_16x16x32_bf16(qf[1][kk], kf, a1, 0, 0, 0);
                }
                s0[f] = a0; s1[f] = a1;
            }

            if ((n0 + 63 > qr0) || (qr0 + 31 - n0 > W)) {
                #pragma unroll
                for (int f = 0; f < 4; ++f) {
                    const int si = n0 + f * 16 + lr;
                    #pragma unroll
                    for (int r = 0; r < 4; ++r) {
                        const int t0i = qr0 + lq * 4 + r;
                        const int t1i = t0i + 16;
                        if (si > t0i || t0i - si > W) s0[f][r] = -1e30f;
                        if (si > t1i || t1i - si > W) s1[f][r] = -1e30f;
                    }
                }
            }

            // fixed-max exponent + P -> LDS (Ps[w] wave-private, no barrier)
            #pragma unroll
            for (int f = 0; f < 4; ++f)
                #pragma unroll
                for (int r = 0; r < 4; ++r) {
                    const float p0 = exp2f(s0[f][r] * CEXP - SMAXS);
                    const float p1 = exp2f(s1[f][r] * CEXP - SMAXS);
                    Ps[w][lq * 4 + r][f * 16 + lr]      = f2b(p0);
                    Ps[w][16 + lq * 4 + r][f * 16 + lr] = f2b(p1);
                }

            // O += P V ; l += P 1 (ones-block)
            bfv8 pf0[2], pf1[2];
            #pragma unroll
            for (int kk2 = 0; kk2 < 2; ++kk2) {
                pf0[kk2] = *(const bfv8*)&Ps[w][lr][kk2 * 32 + lq * 8];
                pf1[kk2] = *(const bfv8*)&Ps[w][16 + lr][kk2 * 32 + lq * 8];
            }
            #pragma unroll
            for (int kk2 = 0; kk2 < 2; ++kk2) {
                #pragma unroll
                for (int od = 0; od < 8; ++od) {
                    bfv8 vf = *(const bfv8*)&VTs[od * 16 + lr][kk2 * 32 + lq * 8];
                    oacc[0][od] = __builtin_amdgcn_mfma_f32_16x16x32_bf16(pf0[kk2], vf, oacc[0][od], 0, 0, 0);
                    oacc[1][od] = __builtin_amdgcn_mfma_f32_16x16x32_bf16(pf1[kk2], vf, oacc[1][od], 0, 0, 0);
                }
                bfv8 vf1 = *(const bfv8*)&VTs[128 + lr][kk2 * 32 + lq * 8];
                lacc[0] = __builtin_amdgcn_mfma_f32_16x16x32_bf16(pf0[kk2], vf1, lacc[0], 0, 0, 0);
                lacc[1] = __builtin_amdgcn_mfma_f32_16x16x32_bf16(pf1[kk2], vf1, lacc[1], 0, 0, 0);
            }
        }
        __syncthreads();
    }

    if (!split) {
        // epilogue: l in lanes lr==0; broadcast + divide, write bf16 y
        #pragma unroll
        for (int mi = 0; mi < 2; ++mi) {
            float linv[4];
            #pragma unroll
            for (int r = 0; r < 4; ++r) {
                const float lv = __shfl(lacc[mi][r], l & 48);
                linv[r] = 1.f / lv;
            }
            #pragma unroll
            for (int od = 0; od < 8; ++od)
                #pragma unroll
                for (int r = 0; r < 4; ++r) {
                    const size_t idx = ((size_t)(b * T_) + qr0 + mi * 16 + lq * 4 + r) * 2048
                                     + h * 128 + od * 16 + lr;
                    yb[idx] = f2b(oacc[mi][od][r] * linv[r]);
                }
        }
    } else {
        // write f32 partial O and l; combined later
        float* op = po + (size_t)i * 16384;
        #pragma unroll
        for (int mi = 0; mi < 2; ++mi) {
            #pragma unroll
            for (int od = 0; od < 8; ++od)
                #pragma unroll
                for (int r = 0; r < 4; ++r)
                    op[(w * 32 + mi * 16 + lq * 4 + r) * 128 + od * 16 + lr] = oacc[mi][od][r];
            if (lr == 0) {
                #pragma unroll
                for (int r = 0; r < 4; ++r)
                    pl[(size_t)i * 128 + w * 32 + mi * 16 + lq * 4 + r] = lacc[mi][r];
            }
        }
    }
}

// ---------------------------------------------------------------------------
// Combine split-K partials for mb 8..15: y = (O_a + O_b) / (l_a + l_b).
// Grid (8, 16, 2) = (mbi, h, b), 256 threads; thread t: row t>>1, col half t&1.
// ---------------------------------------------------------------------------
__global__ __launch_bounds__(256) void attn_combine(
    const float* __restrict__ po, const float* __restrict__ pl, u16* __restrict__ yb)
{
    const int mbi = blockIdx.x, h = blockIdx.y, b = blockIdx.z;
    const int r2 = (b << 7) | (h << 3) | mbi;
    const int mb = 15 - mbi;
    const int t = threadIdx.x;
    const int row = t >> 1;
    const int ch = (t & 1) * 64;
    const float la = pl[(size_t)(r2 * 2) * 128 + row];
    const float lb = pl[(size_t)(r2 * 2 + 1) * 128 + row];
    const float linv = 1.f / (la + lb);
    const float* oa = po + (size_t)(r2 * 2) * 16384 + row * 128 + ch;
    const float* ob = oa + 16384;
    u16* yp = yb + ((size_t)(b * T_) + mb * 128 + row) * 2048 + h * 128 + ch;
    #pragma unroll
    for (int g = 0; g < 8; ++g) {
        const f32x4 a0 = *(const f32x4*)(oa + g * 8);
        const f32x4 a1 = *(const f32x4*)(oa + g * 8 + 4);
        const f32x4 b0 = *(const f32x4*)(ob + g * 8);
        const f32x4 b1 = *(const f32x4*)(ob + g * 8 + 4);
        u16x8 o;
        #pragma unroll
        for (int k = 0; k < 4; ++k) o[k]     = f2b((a0[k] + b0[k]) * linv);
        #pragma unroll
        for (int k = 0; k < 4; ++k) o[4 + k] = f2b((a1[k] + b1[k]) * linv);
        *(u16x8*)(yp + g * 8) = o;
    }
}

// ---------------------------------------------------------------------------
extern "C" void kernel_launch(void* const* d_in, const int* in_sizes, int n_in,
                              void* d_out, int out_size, void* d_ws, size_t ws_size,
                              hipStream_t stream)
{
    const void* x      = d_in[0];
    const void* ve     = d_in[1];
    const void* cosg   = d_in[2];
    const void* sing   = d_in[3];
    const void* w_down = d_in[4];
    const void* w_ukv  = d_in[5];
    const void* w_uq   = d_in[6];
    const void* w_gate = d_in[7];
    const void* w_proj = d_in[8];
    const int*  wsz    = (const int*)d_in[9];
    float* out = (float*)d_out;

    // workspace (~121 MB with aliasing)
    char* p = (char*)d_ws;
    u16* xbf    = (u16*)p; p += (size_t)NT_ * C_ * 2;          // reused as qn
    u16* wcatT  = (u16*)p; p += (size_t)DCATP * C_ * 2;        // [w_down|w_gate|0pad]^T
    u16* wukvT  = (u16*)p; p += (size_t)KV_N * 512 * 2;
    u16* wuqT   = (u16*)p; p += (size_t)Q_N * 512 * 2;
    u16* wpT    = (u16*)p; p += (size_t)C_ * C_ * 2;
    u16* downb  = (u16*)p; p += (size_t)NT_ * DCAT * 2;
    u16* kvb    = (u16*)p; p += (size_t)NT_ * KV_N * 2;
    u16* qraw   = (u16*)p; p += (size_t)NT_ * Q_N * 2;         // reused as vtb
    u16* kn     = (u16*)p; p += (size_t)NT_ * Q_N * 2;
    u16* vn     = (u16*)p; p += (size_t)NT_ * Q_N * 2;         // reused as ybf
    int* flag   = (int*)p; p += 256;
    u16* qn  = xbf;    // x_bf dead after down GEMM
    u16* vtb = qraw;   // qraw dead after assemble
    u16* ybf = vn;     // vn dead after vtrans (attn reads vtb)
    // split-K partials alias downb+kvb (both dead after assemble):
    //   po: 512 * 128 * 128 f32 = 33.55 MB, pl: 512 * 128 f32 = 0.26 MB
    //   downb+kvb region = 34.73 MB  -> fits
    float* attn_po = (float*)downb;
    float* attn_pl = (float*)((char*)downb + (size_t)512 * 16384 * 4);

    dim3 blk(256);
    detect_kernel<<<1, blk, 0, stream>>>((const unsigned*)x, flag);
    cast_kernel<<<dim3(NT_ * C_ / (256 * 8)), blk, 0, stream>>>(x, xbf, NT_ * C_, flag);
    tcast_kernel<<<dim3(DOWN_N / 32, C_ / 32), blk, 0, stream>>>(w_down, wcatT, C_, DOWN_N, DOWN_N, flag);
    // gate cols + zero-pad rows up to DCATP (192 rows total from offset 1088)
    tcast_kernel<<<dim3((DCATP - DOWN_N) / 32, C_ / 32), blk, 0, stream>>>(
        w_gate, wcatT + (size_t)DOWN_N * C_, C_, 80, DCATP - DOWN_N, flag);
    tcast_kernel<<<dim3(KV_N / 32, 512 / 32), blk, 0, stream>>>(w_ukv, wukvT, 512, KV_N, KV_N, flag);
    tcast_kernel<<<dim3(Q_N / 32, 512 / 32), blk, 0, stream>>>(w_uq, wuqT, 512, Q_N, Q_N, flag);
    tcast_kernel<<<dim3(C_ / 32, C_ / 32), blk, 0, stream>>>(w_proj, wpT, C_, C_, C_, flag);

    // down+gates = x @ [w_down|w_gate] -> bf16 [4096,1168] (B padded to 1280 rows)
    mfma_gemm<u16><<<dim3(DCATP / 128, NT_ / 128), blk, 0, stream>>>(
        xbf, C_, wcatT, C_, downb, DCAT, NT_, DCAT, C_);
    // kv = c_kv @ w_ukv -> bf16 [4096,3072]
    mfma_gemm<u16><<<dim3(KV_N / 128, NT_ / 128), blk, 0, stream>>>(
        downb, DCAT, wukvT, 512, kvb, KV_N, NT_, KV_N, 512);
    // q_raw = c_q @ w_uq -> bf16 [4096,2048]
    mfma_gemm<u16><<<dim3(Q_N / 128, NT_ / 128), blk, 0, stream>>>(
        downb + 512, DCAT, wuqT, 512, qraw, Q_N, NT_, Q_N, 512);
    // assemble q/k/v (incl. gate sigmoid from down logits)
    assemble_kernel<<<dim3(NT_), blk, 0, stream>>>(
        downb, qraw, kvb, ve, cosg, sing, qn, kn, vn, flag);
    // v transpose to [(b,h)][d][t]
    vtrans_kernel<<<dim3(T_ / 64, 2, B_ * H_), blk, 0, stream>>>(vn, vtb);
    // flash attention (split-K, 768 blocks) -> y bf16 + f32 partials
    attn_mfma<<<dim3(768), dim3(256), 0, stream>>>(qn, kn, vtb, ybf, attn_po, attn_pl, wsz);
    // combine partials for mb 8..15
    attn_combine<<<dim3(8, 16, 2), blk, 0, stream>>>(attn_po, attn_pl, ybf);
    // out = y @ w_proj -> f32
    mfma_gemm<float><<<dim3(Q_N / 128, NT_ / 128), blk, 0, stream>>>(
        ybf, Q_N, wpT, C_, out, C_, NT_, C_, Q_N);
}